// Round 1
// baseline (2099.220 us; speedup 1.0000x reference)
//
#include <hip/hip_runtime.h>

// ---------------- problem constants ----------------
constexpr int NY = 100, NX = 200;
constexpr int PML = 35;
constexpr int NYP = 170, NXP = 270;          // padded grid
constexpr int S = 2, NREC = 100, NT = 300;
constexpr float DT = 1e-3f, DT2 = DT * DT;

// tiling: 2 shots x 8x8 tiles -> 128 blocks
constexpr int NTY = 8, NTX = 8;
constexpr int TY = 22, TX = 34;              // nominal tile (last row/col smaller)
constexpr int NBLKS = S * NTY * NTX;         // 128
constexpr int THREADS = 512;
constexpr int NC = NT / 2;                   // 150 two-step cycles

// LDS geometry (k=2 time batching: u ring 16, py rows+-12/cols+-8, px rows+-8/cols+-12)
constexpr int UH = TY + 32, UW = TX + 33;    // 54 x 67 (odd stride)
constexpr int PYH = TY + 24, PYS = TX + 17;  // 46 rows, stride 51 (cols -8..C+8)
constexpr int PXH = TY + 16, PXS = TX + 25;  // 38 rows, stride 59 (cols -12..C+12)
constexpr int EH  = TY + 16, ES  = TX + 17;  // apron8 coeff tiles, stride 51
constexpr int GSZ = NYP * NXP;               // 45900

// stencil coefficients, offsets -4..4, pre-scaled by 1/dx^2 and 1/dx
__device__ __constant__ float C2D[9] = {
    (float)(-1.0/560.0/100.0), (float)(8.0/315.0/100.0), (float)(-1.0/5.0/100.0),
    (float)(8.0/5.0/100.0),    (float)(-205.0/72.0/100.0), (float)(8.0/5.0/100.0),
    (float)(-1.0/5.0/100.0),   (float)(8.0/315.0/100.0),  (float)(-1.0/560.0/100.0)};
__device__ __constant__ float C1D[9] = {
    (float)(1.0/280.0/10.0), (float)(-4.0/105.0/10.0), (float)(1.0/5.0/10.0),
    (float)(-4.0/5.0/10.0),  0.0f,                     (float)(4.0/5.0/10.0),
    (float)(-1.0/5.0/10.0),  (float)(4.0/105.0/10.0),  (float)(-1.0/280.0/10.0)};

// ---------------- agent-scope accessors (coherent at Infinity Cache) -------
__device__ __forceinline__ float gload(const float* p) {
    return __hip_atomic_load(p, __ATOMIC_RELAXED, __HIP_MEMORY_SCOPE_AGENT);
}
__device__ __forceinline__ void gstore(float* p, float v) {
    __hip_atomic_store(p, v, __ATOMIC_RELAXED, __HIP_MEMORY_SCOPE_AGENT);
}
__device__ __forceinline__ int iload(const int* p) {
    return __hip_atomic_load(p, __ATOMIC_RELAXED, __HIP_MEMORY_SCOPE_AGENT);
}
__device__ __forceinline__ void istore(int* p, int v) {
    __hip_atomic_store(p, v, __ATOMIC_RELAXED, __HIP_MEMORY_SCOPE_AGENT);
}

__device__ __forceinline__ float sigma_of(int d, int n, float smax) {
    float r = fmaxf(fmaxf((float)(PML - d) / (float)PML,
                          (float)(d - (n - 1 - PML)) / (float)PML), 0.0f);
    return smax * r * r;
}

// ---------------- setup: vmax -> sigma_max ----------------
__global__ void vmax_kernel(const float* __restrict__ vp, float* __restrict__ cst) {
    __shared__ float red[256];
    float m = 0.0f;
    for (int i = threadIdx.x; i < NY * NX; i += 256) m = fmaxf(m, vp[i]);
    red[threadIdx.x] = m;
    __syncthreads();
    for (int s2 = 128; s2 > 0; s2 >>= 1) {
        if (threadIdx.x < s2) red[threadIdx.x] = fmaxf(red[threadIdx.x], red[threadIdx.x + s2]);
        __syncthreads();
    }
    if (threadIdx.x == 0)
        cst[0] = 3.0f * red[0] * logf(1000.0f) / (2.0f * PML * 10.0f);
}

// ------- persistent kernel: 2 time steps per neighbor exchange -------------
__global__ __launch_bounds__(THREADS) void persist_kernel(
    const float* __restrict__ vp, const float* __restrict__ src,
    const int* __restrict__ src_loc, const int* __restrict__ rec_loc,
    float* __restrict__ out, float* __restrict__ Ug, float* __restrict__ PYg,
    float* __restrict__ PXg, const float* __restrict__ cst,
    int* __restrict__ flags) {

    __shared__ float uB[3][UH * UW];          // rotating u(t-1)/u(t)/u(t+1)
    __shared__ float pyB[PYH * PYS];          // py on rows +-12, cols +-8
    __shared__ float pxB[PXH * PXS];          // px on rows +-8,  cols +-12
    __shared__ float eB[EH * ES], dB[EH * ES];// dt^2 v^2, 1/(1+0.5 s dt) on apron8
    __shared__ float syS[UH], byS[UH], bymS[UH];
    __shared__ float sxS[UW], bxS[UW], bxmS[UW];

    const int tid = threadIdx.x;
    const int bid = blockIdx.x;
    const int sh  = bid / (NTY * NTX);
    const int tr  = bid - sh * (NTY * NTX);
    const int tyi = tr / NTX, txi = tr - tyi * NTX;
    const int y0 = tyi * TY, x0 = txi * TX;
    const int R = min(TY, NYP - y0), C = min(TX, NXP - x0);
    const float smax = cst[0];

    // clamped rectangles (global coords)
    const int u_ya = max(0, y0 - 16), u_yb = min(NYP, y0 + R + 16);
    const int u_xa = max(0, x0 - 16), u_xb = min(NXP, x0 + C + 16);
    const int py_ya = max(0, y0 - 12), py_yb = min(NYP, y0 + R + 12);
    const int py_xa = max(0, x0 - 8),  py_xb = min(NXP, x0 + C + 8);
    const int px_ya = max(0, y0 - 8),  px_yb = min(NYP, y0 + R + 8);
    const int px_xa = max(0, x0 - 12), px_xb = min(NXP, x0 + C + 12);
    const int a8_ya = px_ya, a8_yb = px_yb;   // rows +-8
    const int a8_xa = py_xa, a8_xb = py_xb;   // cols +-8
    const int p3_ya = max(0, y0 - 4), p3_yb = min(NYP, y0 + R + 4);
    const int p3_xa = max(0, x0 - 4), p3_xb = min(NXP, x0 + C + 4);

    // zero LDS (out-of-domain cells stay 0 forever; loops below are clamped)
    for (int i = tid; i < 3 * UH * UW; i += THREADS) ((float*)uB)[i] = 0.0f;
    for (int i = tid; i < PYH * PYS; i += THREADS) pyB[i] = 0.0f;
    for (int i = tid; i < PXH * PXS; i += THREADS) pxB[i] = 0.0f;

    for (int i = tid; i < UH; i += THREADS) {
        int gy = y0 - 16 + i;
        float sg = sigma_of(gy, NYP, smax);
        syS[i] = sg;
        if (gy >= 0 && gy < NYP) { float b = __expf(-sg * DT); byS[i] = b; bymS[i] = b - 1.0f; }
        else { byS[i] = 0.0f; bymS[i] = 0.0f; }
    }
    for (int i = tid; i < UW; i += THREADS) {
        int gx = x0 - 16 + i;
        float sg = sigma_of(gx, NXP, smax);
        sxS[i] = sg;
        if (gx >= 0 && gx < NXP) { float b = __expf(-sg * DT); bxS[i] = b; bxmS[i] = b - 1.0f; }
        else { bxS[i] = 0.0f; bxmS[i] = 0.0f; }
    }
    {   // e, d on apron8
        const int W = a8_xb - a8_xa, n = (a8_yb - a8_ya) * W;
        for (int i = tid; i < n; i += THREADS) {
            int ry = i / W, gy = a8_ya + ry, gx = a8_xa + (i - ry * W);
            int vy = min(max(gy - PML, 0), NY - 1), vx = min(max(gx - PML, 0), NX - 1);
            float v = vp[vy * NX + vx];
            int ei = (gy - y0 + 8) * ES + (gx - x0 + 8);
            eB[ei] = DT2 * v * v;
            float s_ = sigma_of(gy, NYP, smax) + sigma_of(gx, NXP, smax);
            dB[ei] = 1.0f / (1.0f + 0.5f * s_ * DT);
        }
    }

    const int sgy = src_loc[sh * 2 + 0] + PML, sgx = src_loc[sh * 2 + 1] + PML;
    const float* srcRow = src + sh * NT;

    int recLds = -1, recOut = 0;
    if (tid < S * NREC) {
        int rs = tid / NREC, rr = tid - rs * NREC;
        int ry = rec_loc[(rs * NREC + rr) * 2 + 0] + PML;
        int rx = rec_loc[(rs * NREC + rr) * 2 + 1] + PML;
        if (rs == sh && ry >= y0 && ry < y0 + R && rx >= x0 && rx < x0 + C) {
            recLds = (ry - y0 + 16) * UW + (rx - x0 + 16);
            recOut = rs * NT * NREC + rr;
        }
    }

    float *uC = uB[0], *uP = uB[1], *uN = uB[2];

    if (tid == 0) istore(&flags[bid], 1);   // parity-0 grid (host memset zeros) ready
    __syncthreads();

    for (int cyc = 0; cyc < NC; ++cyc) {
        const int p = cyc & 1;
        const float* Ur  = Ug  + (size_t)(p * S + sh) * GSZ;
        float*       Uw  = Ug  + (size_t)((p ^ 1) * S + sh) * GSZ;
        const float* PYr = PYg + (size_t)(p * S + sh) * GSZ;
        float*       PYw = PYg + (size_t)((p ^ 1) * S + sh) * GSZ;
        const float* PXr = PXg + (size_t)(p * S + sh) * GSZ;
        float*       PXw = PXg + (size_t)((p ^ 1) * S + sh) * GSZ;

        // ---- poll all 8 neighbors (corners matter for ring reads) ----
        if (tid < 8) {
            int idx = tid < 4 ? tid : tid + 1;         // skip (0,0)
            int dy = idx / 3 - 1, dx = idx - (idx / 3) * 3 - 1;
            int ty2 = tyi + dy, tx2 = txi + dx;
            if (ty2 >= 0 && ty2 < NTY && tx2 >= 0 && tx2 < NTX) {
                int nb = bid + dy * NTX + dx;
                while (iload(&flags[nb]) < cyc + 1) { }
            }
        }
        __syncthreads();                               // B1

        // ---- ring reads: u(t) ring16, py(t)/px(t) rings ----
        {
            const int W = u_xb - u_xa, n = (u_yb - u_ya) * W;
            for (int i = tid; i < n; i += THREADS) {
                int ry = i / W, gy = u_ya + ry, gx = u_xa + (i - ry * W);
                int ly = gy - y0, lx = gx - x0;
                if ((unsigned)ly < (unsigned)R && (unsigned)lx < (unsigned)C) continue;
                uC[(ly + 16) * UW + (lx + 16)] = gload(Ur + gy * NXP + gx);
            }
        }
        {
            const int W = py_xb - py_xa, n = (py_yb - py_ya) * W;
            for (int i = tid; i < n; i += THREADS) {
                int ry = i / W, gy = py_ya + ry, gx = py_xa + (i - ry * W);
                int ly = gy - y0, lx = gx - x0;
                if ((unsigned)ly < (unsigned)R && (unsigned)lx < (unsigned)C) continue;
                pyB[(ly + 12) * PYS + (lx + 8)] = gload(PYr + gy * NXP + gx);
            }
        }
        {
            const int W = px_xb - px_xa, n = (px_yb - px_ya) * W;
            for (int i = tid; i < n; i += THREADS) {
                int ry = i / W, gy = px_ya + ry, gx = px_xa + (i - ry * W);
                int ly = gy - y0, lx = gx - x0;
                if ((unsigned)ly < (unsigned)R && (unsigned)lx < (unsigned)C) continue;
                pxB[(ly + 8) * PXS + (lx + 12)] = gload(PXr + gy * NXP + gx);
            }
        }
        __syncthreads();                               // B2

        // ---- sub-step 0, phase 1: py' on [+-12]x[+-8], px' on [+-8]x[+-12]
        {
            const int W = py_xb - py_xa, n = (py_yb - py_ya) * W;
            for (int i = tid; i < n; i += THREADS) {
                int ry = i / W, gy = py_ya + ry, gx = py_xa + (i - ry * W);
                int ly = gy - y0, lx = gx - x0;
                const float* ucol = &uC[(ly + 12) * UW + (lx + 16)];
                float d1a = 0.0f, d1b = 0.0f;
#pragma unroll
                for (int k = 0; k < 4; k++) {
                    d1a = fmaf(C1D[k],     ucol[k * UW],       d1a);
                    d1b = fmaf(C1D[k + 5], ucol[(k + 5) * UW], d1b);
                }
                int pi = (ly + 12) * PYS + (lx + 8);
                pyB[pi] = fmaf(byS[ly + 16], pyB[pi], bymS[ly + 16] * (d1a + d1b));
            }
        }
        {
            const int W = px_xb - px_xa, n = (px_yb - px_ya) * W;
            for (int i = tid; i < n; i += THREADS) {
                int ry = i / W, gy = px_ya + ry, gx = px_xa + (i - ry * W);
                int ly = gy - y0, lx = gx - x0;
                const float* urow = &uC[(ly + 16) * UW + (lx + 12)];
                float d1a = 0.0f, d1b = 0.0f;
#pragma unroll
                for (int k = 0; k < 4; k++) {
                    d1a = fmaf(C1D[k],     urow[k],     d1a);
                    d1b = fmaf(C1D[k + 5], urow[k + 5], d1b);
                }
                int pi = (ly + 8) * PXS + (lx + 12);
                pxB[pi] = fmaf(bxS[lx + 16], pxB[pi], bxmS[lx + 16] * (d1a + d1b));
            }
        }
        __syncthreads();                               // B3

        // ---- sub-step 0, phase 2: u(t+1) on full apron8 (incl corners) ----
        {
            const float f0 = srcRow[2 * cyc];
            const int W = a8_xb - a8_xa, n = (a8_yb - a8_ya) * W;
            for (int i = tid; i < n; i += THREADS) {
                int ry = i / W, gy = a8_ya + ry, gx = a8_xa + (i - ry * W);
                int ly = gy - y0, lx = gx - x0;
                const int ub = (ly + 16) * UW + (lx + 16);
                const float* uc  = &uC[ub];
                const float* pyc = &pyB[(ly + 8) * PYS + (lx + 8)];
                const float* pxc = &pxB[(ly + 8) * PXS + (lx + 8)];
                float d2y = 0.0f, d2x = 0.0f, d1py = 0.0f, d1px = 0.0f;
#pragma unroll
                for (int k = 0; k < 9; k++) {
                    d2y = fmaf(C2D[k], uc[(k - 4) * UW], d2y);
                    d2x = fmaf(C2D[k], uc[k - 4], d2x);
                    if (k != 4) {
                        d1py = fmaf(C1D[k], pyc[k * PYS], d1py);
                        d1px = fmaf(C1D[k], pxc[k], d1px);
                    }
                }
                float lap = (d2y + d2x) + (d1py + d1px);
                float sy = syS[ly + 16], sx = sxS[lx + 16];
                float Av = 2.0f - sy * sx * DT2, Bv = 1.0f - 0.5f * (sy + sx) * DT;
                int ei = (ly + 8) * ES + (lx + 8);
                float f = (gy == sgy && gx == sgx) ? f0 : 0.0f;
                uN[ub] = (Av * uc[0] - Bv * uP[ub] + eB[ei] * (lap + f)) * dB[ei];
            }
        }
        __syncthreads();                               // B4

        // ---- sub-step 1, phase 3: py''/px'' + fused push of tile values ----
        {
            const int n = (p3_yb - p3_ya) * C;
            for (int i = tid; i < n; i += THREADS) {
                int ry = i / C, gy = p3_ya + ry, gx = x0 + (i - ry * C);
                int ly = gy - y0, lx = gx - x0;
                const float* ucol = &uN[(ly + 12) * UW + (lx + 16)];
                float d1a = 0.0f, d1b = 0.0f;
#pragma unroll
                for (int k = 0; k < 4; k++) {
                    d1a = fmaf(C1D[k],     ucol[k * UW],       d1a);
                    d1b = fmaf(C1D[k + 5], ucol[(k + 5) * UW], d1b);
                }
                int pi = (ly + 12) * PYS + (lx + 8);
                float v = fmaf(byS[ly + 16], pyB[pi], bymS[ly + 16] * (d1a + d1b));
                pyB[pi] = v;
                if ((unsigned)ly < (unsigned)R) gstore(PYw + gy * NXP + gx, v);
            }
        }
        {
            const int W = p3_xb - p3_xa, n = R * W;
            for (int i = tid; i < n; i += THREADS) {
                int ry = i / W, gy = y0 + ry, gx = p3_xa + (i - ry * W);
                int ly = gy - y0, lx = gx - x0;
                const float* urow = &uN[(ly + 16) * UW + (lx + 12)];
                float d1a = 0.0f, d1b = 0.0f;
#pragma unroll
                for (int k = 0; k < 4; k++) {
                    d1a = fmaf(C1D[k],     urow[k],     d1a);
                    d1b = fmaf(C1D[k + 5], urow[k + 5], d1b);
                }
                int pi = (ly + 8) * PXS + (lx + 12);
                float v = fmaf(bxS[lx + 16], pxB[pi], bxmS[lx + 16] * (d1a + d1b));
                pxB[pi] = v;
                if ((unsigned)lx < (unsigned)C) gstore(PXw + gy * NXP + gx, v);
            }
        }
        __syncthreads();                               // B5

        // ---- sub-step 1, phase 4: u(t+2) on tile + fused push ----
        {
            const float f1 = srcRow[2 * cyc + 1];
            const int n = R * C;
            for (int i = tid; i < n; i += THREADS) {
                int ry = i / C, gy = y0 + ry, gx = x0 + (i - ry * C);
                int ly = ry, lx = gx - x0;
                const int ub = (ly + 16) * UW + (lx + 16);
                const float* uc  = &uN[ub];
                const float* pyc = &pyB[(ly + 8) * PYS + (lx + 8)];
                const float* pxc = &pxB[(ly + 8) * PXS + (lx + 8)];
                float d2y = 0.0f, d2x = 0.0f, d1py = 0.0f, d1px = 0.0f;
#pragma unroll
                for (int k = 0; k < 9; k++) {
                    d2y = fmaf(C2D[k], uc[(k - 4) * UW], d2y);
                    d2x = fmaf(C2D[k], uc[k - 4], d2x);
                    if (k != 4) {
                        d1py = fmaf(C1D[k], pyc[k * PYS], d1py);
                        d1px = fmaf(C1D[k], pxc[k], d1px);
                    }
                }
                float lap = (d2y + d2x) + (d1py + d1px);
                float sy = syS[ly + 16], sx = sxS[lx + 16];
                float Av = 2.0f - sy * sx * DT2, Bv = 1.0f - 0.5f * (sy + sx) * DT;
                int ei = (ly + 8) * ES + (lx + 8);
                float f = (gy == sgy && gx == sgx) ? f1 : 0.0f;
                float un = (Av * uc[0] - Bv * uC[ub] + eB[ei] * (lap + f)) * dB[ei];
                uP[ub] = un;
                gstore(Uw + gy * NXP + gx, un);
            }
        }
        __syncthreads();                               // B6: drains pushes (vmcnt 0)
        if (tid == 0) istore(&flags[bid], cyc + 2);

        // ---- receivers: out rows 2c (u(t+1) in uN) and 2c+1 (u(t+2) in uP)
        if (recLds >= 0) {
            out[recOut + (2 * cyc) * NREC]     = uN[recLds];
            out[recOut + (2 * cyc + 1) * NREC] = uP[recLds];
        }

        // rotate: cur <- u(t+2) (ring refilled next cycle), prev <- u(t+1) apron8
        float* tmp = uC; uC = uP; uP = uN; uN = tmp;
    }
}

// ---------------- host launch ----------------
extern "C" void kernel_launch(void* const* d_in, const int* in_sizes, int n_in,
                              void* d_out, int out_size, void* d_ws, size_t ws_size,
                              hipStream_t stream) {
    const float* vp = (const float*)d_in[0];
    const float* src = (const float*)d_in[1];
    const int* src_loc = (const int*)d_in[2];
    const int* rec_loc = (const int*)d_in[3];
    float* out = (float*)d_out;

    float* ws = (float*)d_ws;
    float* cst   = ws;                        // 16 floats
    int*   flags = (int*)(ws + 16);           // NBLKS ints
    float* Ug  = ws + 16 + NBLKS;             // [2 parity][S][GSZ]
    float* PYg = Ug + (size_t)2 * S * GSZ;
    float* PXg = PYg + (size_t)2 * S * GSZ;

    const size_t totalF = 16 + NBLKS + (size_t)3 * 2 * S * GSZ;
    hipMemsetAsync(d_ws, 0, totalF * sizeof(float), stream);
    vmax_kernel<<<1, 256, 0, stream>>>(vp, cst);
    persist_kernel<<<NBLKS, THREADS, 0, stream>>>(
        vp, src, src_loc, rec_loc, out, Ug, PYg, PXg, cst, flags);
}

// Round 2
// 1459.588 us; speedup vs baseline: 1.4382x; 1.4382x over previous
//
#include <hip/hip_runtime.h>

// ---------------- problem constants ----------------
constexpr int NY = 100, NX = 200;
constexpr int PML = 35;
constexpr int NYP = 170, NXP = 270;          // padded grid
constexpr int S = 2, NREC = 100, NT = 300;
constexpr float DX = 10.0f, DT = 1e-3f, DT2 = DT * DT;

// tiling: 2 shots x 8x8 tiles -> 128 blocks (round-6-proven config)
constexpr int NTY = 8, NTX = 8;
constexpr int TY = 22, TX = 34;              // nominal tile (last row/col smaller)
constexpr int NBLKS = S * NTY * NTX;         // 128
constexpr int THREADS = 512;
constexpr int FSTR = 32;                     // flag stride: 1 flag per 128B line

constexpr int UW = TX + 17;                  // 51 (odd): u LDS row stride, 8-halo each side
constexpr int UH = TY + 16;                  // 38
constexpr int PYH = TY + 8;                  // 30: py on +/-4-row apron
constexpr int PXW = TX + 8;                  // 42: px on +/-4-col apron

// global staging strips (u only; py/px never exchanged)
constexpr int STRIDE_NS = 8 * TX;            // 272
constexpr int STRIDE_WE = TY * 8;            // 176
constexpr int STAGE_STRIDE = 2 * STRIDE_NS + 2 * STRIDE_WE;  // 896
constexpr int OFF_N = 0, OFF_S = STRIDE_NS;
constexpr int OFF_W = 2 * STRIDE_NS, OFF_E = 2 * STRIDE_NS + STRIDE_WE;

// stencil coefficients, offsets -4..4, pre-scaled by 1/dx^2 and 1/dx
__device__ __constant__ float C2D[9] = {
    (float)(-1.0/560.0/100.0), (float)(8.0/315.0/100.0), (float)(-1.0/5.0/100.0),
    (float)(8.0/5.0/100.0),    (float)(-205.0/72.0/100.0), (float)(8.0/5.0/100.0),
    (float)(-1.0/5.0/100.0),   (float)(8.0/315.0/100.0),  (float)(-1.0/560.0/100.0)};
__device__ __constant__ float C1D[9] = {
    (float)(1.0/280.0/10.0), (float)(-4.0/105.0/10.0), (float)(1.0/5.0/10.0),
    (float)(-4.0/5.0/10.0),  0.0f,                     (float)(4.0/5.0/10.0),
    (float)(-1.0/5.0/10.0),  (float)(4.0/105.0/10.0),  (float)(-1.0/280.0/10.0)};

// ---------------- L1/L2-bypassing accessors (coherent at Infinity Cache) ----
__device__ __forceinline__ float gload(const float* p) {
    return __hip_atomic_load(p, __ATOMIC_RELAXED, __HIP_MEMORY_SCOPE_AGENT);
}
__device__ __forceinline__ void gstore(float* p, float v) {
    __hip_atomic_store(p, v, __ATOMIC_RELAXED, __HIP_MEMORY_SCOPE_AGENT);
}
__device__ __forceinline__ int iload(const int* p) {
    return __hip_atomic_load(p, __ATOMIC_RELAXED, __HIP_MEMORY_SCOPE_AGENT);
}
__device__ __forceinline__ void istore(int* p, int v) {
    __hip_atomic_store(p, v, __ATOMIC_RELAXED, __HIP_MEMORY_SCOPE_AGENT);
}

__device__ __forceinline__ float sigma_of(int d, int n, float smax) {
    float r = fmaxf(fmaxf((float)(PML - d) / (float)PML,
                          (float)(d - (n - 1 - PML)) / (float)PML), 0.0f);
    return smax * r * r;
}

// ---------------- setup: vmax -> sigma_max ----------------
__global__ void vmax_kernel(const float* __restrict__ vp, float* __restrict__ cst) {
    __shared__ float red[256];
    float m = 0.0f;
    for (int i = threadIdx.x; i < NY * NX; i += 256) m = fmaxf(m, vp[i]);
    red[threadIdx.x] = m;
    __syncthreads();
    for (int s2 = 128; s2 > 0; s2 >>= 1) {
        if (threadIdx.x < s2) red[threadIdx.x] = fmaxf(red[threadIdx.x], red[threadIdx.x + s2]);
        __syncthreads();
    }
    if (threadIdx.x == 0)
        cst[0] = 3.0f * red[0] * logf(1000.0f) / (2.0f * PML * DX);
}

// ------- persistent LDS-tile kernel, k=1 exchange, latency-hiding schedule --
__global__ __launch_bounds__(THREADS) void persist_kernel(
    const float* __restrict__ vp, const float* __restrict__ src,
    const int* __restrict__ src_loc, const int* __restrict__ rec_loc,
    float* __restrict__ out, float* __restrict__ stage,
    const float* __restrict__ cst, int* __restrict__ flags) {

    __shared__ float uS[2][UH * UW];      // u(t) / u(t-1)->u(t+1), swap each step
    __shared__ float pyS[PYH * TX];       // py on row apron [-4, rows+4)
    __shared__ float pxS[TY * PXW];       // px on col apron [-4, cols+4)
    __shared__ float eS[TY * TX];         // dt^2 * v^2
    __shared__ float dS[TY * TX];         // 1/(1+0.5*s*dt)
    __shared__ float syS[TY], sxS[TX];
    __shared__ float byS[PYH], bymS[PYH], bxS[PXW], bxmS[PXW];

    const int tid = threadIdx.x;
    const int bid = blockIdx.x;
    const int sh  = bid / (NTY * NTX);
    const int tr  = bid - sh * (NTY * NTX);
    const int tyi = tr / NTX, txi = tr - tyi * NTX;
    const int y0 = tyi * TY, x0 = txi * TX;
    const int rows = min(TY, NYP - y0), cols = min(TX, NXP - x0);
    const float smax = cst[0];

    // zero LDS state (domain-boundary halos stay 0 forever)
    for (int i = tid; i < 2 * UH * UW; i += THREADS) ((float*)uS)[i] = 0.0f;
    for (int i = tid; i < PYH * TX; i += THREADS) pyS[i] = 0.0f;
    for (int i = tid; i < TY * PXW; i += THREADS) pxS[i] = 0.0f;

    if (tid < TY) syS[tid] = sigma_of(y0 + tid, NYP, smax);
    if (tid < TX) sxS[tid] = sigma_of(x0 + tid, NXP, smax);
    if (tid < PYH) {
        int yy = y0 - 4 + tid;
        if (yy >= 0 && yy < NYP) {
            float b = __expf(-sigma_of(yy, NYP, smax) * DT);
            byS[tid] = b; bymS[tid] = b - 1.0f;
        } else { byS[tid] = 0.0f; bymS[tid] = 0.0f; }
    }
    if (tid < PXW) {
        int xx = x0 - 4 + tid;
        if (xx >= 0 && xx < NXP) {
            float b = __expf(-sigma_of(xx, NXP, smax) * DT);
            bxS[tid] = b; bxmS[tid] = b - 1.0f;
        } else { bxS[tid] = 0.0f; bxmS[tid] = 0.0f; }
    }
    for (int i = tid; i < rows * cols; i += THREADS) {
        int rr = i / cols, cc = i - rr * cols;
        int gy = y0 + rr, gx = x0 + cc;
        int vy = min(max(gy - PML, 0), NY - 1), vx = min(max(gx - PML, 0), NX - 1);
        float v = vp[vy * NX + vx];
        eS[rr * TX + cc] = DT2 * v * v;
        float s_ = sigma_of(gy, NYP, smax) + sigma_of(gx, NXP, smax);
        dS[rr * TX + cc] = 1.0f / (1.0f + 0.5f * s_ * DT);
    }

    // source (NSRC == 1 per shot)
    const int sy = src_loc[sh * 2 + 0] + PML, sx = src_loc[sh * 2 + 1] + PML;
    const bool ownSrc = (sy >= y0 && sy < y0 + rows && sx >= x0 && sx < x0 + cols);
    const int sLy = sy - y0, sLx = sx - x0;
    const float* srcRow = src + sh * NT;

    // receiver: thread tid handles global receiver tid (<=1 per thread)
    int recLds = -1, recOut = 0;
    if (tid < S * NREC) {
        int rs = tid / NREC, rr2 = tid - rs * NREC;
        int ry = rec_loc[(rs * NREC + rr2) * 2 + 0] + PML;
        int rx = rec_loc[(rs * NREC + rr2) * 2 + 1] + PML;
        if (rs == sh && ry >= y0 && ry < y0 + rows && rx >= x0 && rx < x0 + cols) {
            recLds = (ry - y0 + 8) * UW + (rx - x0 + 8);
            recOut = rs * NT * NREC + rr2;
        }
    }

    const int bN = (tyi > 0)       ? bid - NTX : -1;
    const int bS = (tyi < NTY - 1) ? bid + NTX : -1;
    const int bW = (txi > 0)       ? bid - 1   : -1;
    const int bE = (txi < NTX - 1) ? bid + 1   : -1;

    const int nStr = (rows + 1) >> 1;     // 2-row strips
    const int nBTasks = nStr * cols;      // <= 11*34 = 374 <= THREADS (one round)
    const int nNS = 8 * cols, nWE = rows * 8;

    // per-thread phase-B task coords (t-invariant)
    const bool hasTask = (tid < nBTasks);
    const int sy2 = hasTask ? tid / cols : 0;
    const int cc0 = hasTask ? tid - sy2 * cols : 0;
    const int yb  = 2 * sy2;
    const int nr  = hasTask ? min(2, rows - yb) : 0;
    // interior task: both rows and all +/-4 taps stay in owned/interior region
    const bool isInt = hasTask && (yb >= 8) && (yb + 2 <= rows - 8) &&
                       (cc0 >= 8) && (cc0 < cols - 8);

    // per-wave poll assignment (lanes 0..3 watch N/S/W/E)
    const int lane = tid & 63;
    int pollNb = -1;
    if (lane == 0) pollNb = bN;
    else if (lane == 1) pollNb = bS;
    else if (lane == 2) pollNb = bW;
    else if (lane == 3) pollNb = bE;

    // prologue: stage pre-zeroed by host memset = u(0) strips; announce them.
    if (tid == 0) istore(&flags[bid * FSTR], 1);
    __syncthreads();

    int pa = 0;
    for (int t = 0; t < NT; t++) {
        const int par = t & 1;                 // slot holding u(t) strips
        float* uCur = uS[pa];
        float* uN   = uS[pa ^ 1];              // holds um; overwritten with un

        // ---- 1. phase A interior (no halo dep) ----
        {
            const int nPyI = (rows - 8) * cols, nPxI = rows * (cols - 8);
            for (int i = tid; i < nPyI + nPxI; i += THREADS) {
                if (i < nPyI) {
                    int a = i / cols, cc = i - a * cols, p = 8 + a;
                    float d1a = 0.0f, d1b = 0.0f;
#pragma unroll
                    for (int k = 0; k < 4; k++) {
                        d1a = fmaf(C1D[k],     uCur[(p + k)     * UW + 8 + cc], d1a);
                        d1b = fmaf(C1D[k + 5], uCur[(p + k + 5) * UW + 8 + cc], d1b);
                    }
                    pyS[p * TX + cc] = fmaf(byS[p], pyS[p * TX + cc], bymS[p] * (d1a + d1b));
                } else {
                    int j = i - nPyI;
                    int rr = j / (cols - 8), q = 8 + (j - rr * (cols - 8));
                    float d1a = 0.0f, d1b = 0.0f;
#pragma unroll
                    for (int k = 0; k < 4; k++) {
                        d1a = fmaf(C1D[k],     uCur[(8 + rr) * UW + q + k],     d1a);
                        d1b = fmaf(C1D[k + 5], uCur[(8 + rr) * UW + q + k + 5], d1b);
                    }
                    pxS[rr * PXW + q] = fmaf(bxS[q], pxS[rr * PXW + q], bxmS[q] * (d1a + d1b));
                }
            }
        }
        __syncthreads();                       // B_a: A-interior visible

        // ---- 2. phase B interior (no halo dep, no push) ----
        if (isInt) {
            float ucol[10], pycol[10];
#pragma unroll
            for (int i2 = 0; i2 < 10; i2++) ucol[i2] = uCur[(yb + 4 + i2) * UW + 8 + cc0];
#pragma unroll
            for (int i2 = 0; i2 < 10; i2++) pycol[i2] = pyS[(yb + i2) * TX + cc0];
            const float sxv = sxS[cc0];
#pragma unroll
            for (int i2 = 0; i2 < 2; i2++) {
                const int ly = yb + i2;
                float d2y = 0.0f, d2x = 0.0f, d1py = 0.0f, d1px = 0.0f;
                const float* urow = &uCur[(8 + ly) * UW + 8 + cc0 - 4];
                const float* pxrow = &pxS[ly * PXW + cc0];
#pragma unroll
                for (int k = 0; k < 9; k++) {
                    d2y = fmaf(C2D[k], ucol[i2 + k], d2y);
                    d2x = fmaf(C2D[k], urow[k], d2x);
                    if (k != 4) {
                        d1py = fmaf(C1D[k], pycol[i2 + k], d1py);
                        d1px = fmaf(C1D[k], pxrow[k], d1px);
                    }
                }
                const float lap = (d2y + d2x) + (d1py + d1px);
                const float syv = syS[ly];
                const float s_ = syv + sxv, pr = syv * sxv;
                const float Av = 2.0f - pr * DT2;
                const float Bv = 1.0f - 0.5f * s_ * DT;
                const float f = (ownSrc && ly == sLy && cc0 == sLx) ? srcRow[t] : 0.0f;
                const int ci = (8 + ly) * UW + 8 + cc0;
                const float umv = uN[ci];
                uN[ci] = (Av * ucol[i2 + 4] - Bv * umv +
                          eS[ly * TX + cc0] * (lap + f)) * dS[ly * TX + cc0];
            }
        }

        // ---- 3. per-wave neighbor poll (no barrier; flags padded) ----
        {
            bool done = (pollNb < 0);
            while (!__all(done ? 1 : 0)) {
                if (!done) done = (iload(&flags[pollNb * FSTR]) >= t + 1);
            }
        }

        // ---- 4. read neighbor strips (u(t)) into u halos ----
        if (bN >= 0) {
            const float* nb = stage + (size_t)(bN * 2 + par) * STAGE_STRIDE + OFF_S;
            for (int i = tid; i < nNS; i += THREADS) {
                int r2 = i / cols, c2 = i - r2 * cols;
                uCur[r2 * UW + 8 + c2] = gload(nb + r2 * TX + c2);
            }
        }
        if (bS >= 0) {
            const float* nb = stage + (size_t)(bS * 2 + par) * STAGE_STRIDE + OFF_N;
            for (int i = tid; i < nNS; i += THREADS) {
                int r2 = i / cols, c2 = i - r2 * cols;
                uCur[(8 + rows + r2) * UW + 8 + c2] = gload(nb + r2 * TX + c2);
            }
        }
        if (bW >= 0) {
            const float* nb = stage + (size_t)(bW * 2 + par) * STAGE_STRIDE + OFF_E;
            for (int i = tid; i < nWE; i += THREADS)
                uCur[(8 + (i >> 3)) * UW + (i & 7)] = gload(nb + i);
        }
        if (bE >= 0) {
            const float* nb = stage + (size_t)(bE * 2 + par) * STAGE_STRIDE + OFF_W;
            for (int i = tid; i < nWE; i += THREADS)
                uCur[(8 + (i >> 3)) * UW + 8 + cols + (i & 7)] = gload(nb + i);
        }
        __syncthreads();                       // B2: halo complete

        // ---- 5. phase A border (needs fresh halo) ----
        {
            const int n0 = 8 * cols, n2 = rows * 8;
            for (int i = tid; i < 2 * n0 + 2 * n2; i += THREADS) {
                int j = i, p = -1, cc = 0, q = 0, rr = 0;
                if (j < n0)              { int a = j / cols; p = a;        cc = j - a * cols; }
                else if ((j -= n0) < n0) { int a = j / cols; p = rows + a; cc = j - a * cols; }
                else if ((j -= n0) < n2) { rr = j >> 3; q = j & 7; }
                else                     { j -= n2; rr = j >> 3; q = cols + (j & 7); }
                if (p >= 0) {
                    float d1a = 0.0f, d1b = 0.0f;
#pragma unroll
                    for (int k = 0; k < 4; k++) {
                        d1a = fmaf(C1D[k],     uCur[(p + k)     * UW + 8 + cc], d1a);
                        d1b = fmaf(C1D[k + 5], uCur[(p + k + 5) * UW + 8 + cc], d1b);
                    }
                    pyS[p * TX + cc] = fmaf(byS[p], pyS[p * TX + cc], bymS[p] * (d1a + d1b));
                } else {
                    float d1a = 0.0f, d1b = 0.0f;
#pragma unroll
                    for (int k = 0; k < 4; k++) {
                        d1a = fmaf(C1D[k],     uCur[(8 + rr) * UW + q + k],     d1a);
                        d1b = fmaf(C1D[k + 5], uCur[(8 + rr) * UW + q + k + 5], d1b);
                    }
                    pxS[rr * PXW + q] = fmaf(bxS[q], pxS[rr * PXW + q], bxmS[q] * (d1a + d1b));
                }
            }
        }
        __syncthreads();                       // B3

        // ---- 6. phase B border + fused strip push ----
        float* sb = stage + (size_t)(bid * 2 + ((t + 1) & 1)) * STAGE_STRIDE;
        if (hasTask && !isInt) {
            float ucol[10], pycol[10];
#pragma unroll
            for (int i2 = 0; i2 < 10; i2++) ucol[i2] = uCur[(yb + 4 + i2) * UW + 8 + cc0];
#pragma unroll
            for (int i2 = 0; i2 < 10; i2++) pycol[i2] = pyS[(yb + i2) * TX + cc0];
            const float sxv = sxS[cc0];
            for (int i2 = 0; i2 < nr; i2++) {
                const int ly = yb + i2;
                float d2y = 0.0f, d2x = 0.0f, d1py = 0.0f, d1px = 0.0f;
                const float* urow = &uCur[(8 + ly) * UW + 8 + cc0 - 4];
                const float* pxrow = &pxS[ly * PXW + cc0];
#pragma unroll
                for (int k = 0; k < 9; k++) {
                    d2y = fmaf(C2D[k], ucol[i2 + k], d2y);
                    d2x = fmaf(C2D[k], urow[k], d2x);
                    if (k != 4) {
                        d1py = fmaf(C1D[k], pycol[i2 + k], d1py);
                        d1px = fmaf(C1D[k], pxrow[k], d1px);
                    }
                }
                const float lap = (d2y + d2x) + (d1py + d1px);
                const float syv = syS[ly];
                const float s_ = syv + sxv, pr = syv * sxv;
                const float Av = 2.0f - pr * DT2;
                const float Bv = 1.0f - 0.5f * s_ * DT;
                const float f = (ownSrc && ly == sLy && cc0 == sLx) ? srcRow[t] : 0.0f;
                const int ci = (8 + ly) * UW + 8 + cc0;
                const float umv = uN[ci];
                const float unv = (Av * ucol[i2 + 4] - Bv * umv +
                                   eS[ly * TX + cc0] * (lap + f)) * dS[ly * TX + cc0];
                uN[ci] = unv;
                // fused strip push (u(t+1) ring cells, from register)
                if (ly < 8)           gstore(sb + OFF_N + ly * TX + cc0, unv);
                if (ly >= rows - 8)   gstore(sb + OFF_S + (ly - (rows - 8)) * TX + cc0, unv);
                if (cc0 < 8)          gstore(sb + OFF_W + ly * 8 + cc0, unv);
                if (cc0 >= cols - 8)  gstore(sb + OFF_E + ly * 8 + (cc0 - (cols - 8)), unv);
            }
        }
        __syncthreads();                       // B4: drains strip stores (vmcnt 0)
        if (tid == 0 && t + 1 < NT) istore(&flags[bid * FSTR], t + 2);

        // ---- 7. receivers sample un ----
        if (recLds >= 0) out[recOut + t * NREC] = uN[recLds];

        pa ^= 1;
    }
}

// ---------------- host launch ----------------
extern "C" void kernel_launch(void* const* d_in, const int* in_sizes, int n_in,
                              void* d_out, int out_size, void* d_ws, size_t ws_size,
                              hipStream_t stream) {
    const float* vp = (const float*)d_in[0];
    const float* src = (const float*)d_in[1];
    const int* src_loc = (const int*)d_in[2];
    const int* rec_loc = (const int*)d_in[3];
    float* out = (float*)d_out;

    float* ws = (float*)d_ws;
    float* cst   = ws;                       // 16 floats
    int*   flags = (int*)(ws + 16);          // NBLKS * FSTR ints (padded flags)
    float* stage = ws + 16 + NBLKS * FSTR;   // NBLKS*2*STAGE_STRIDE floats

    // zero cst + flags + stage (stage zeros = u(0) border strips)
    hipMemsetAsync(d_ws, 0,
                   (size_t)(16 + NBLKS * FSTR + NBLKS * 2 * STAGE_STRIDE) * sizeof(float),
                   stream);
    vmax_kernel<<<1, 256, 0, stream>>>(vp, cst);
    persist_kernel<<<NBLKS, THREADS, 0, stream>>>(
        vp, src, src_loc, rec_loc, out, stage, cst, flags);
}

// Round 3
// 1252.591 us; speedup vs baseline: 1.6759x; 1.1653x over previous
//
#include <hip/hip_runtime.h>

// ---------------- problem constants ----------------
constexpr int NY = 100, NX = 200;
constexpr int PML = 35;
constexpr int NYP = 170, NXP = 270;          // padded grid
constexpr int S = 2, NREC = 100, NT = 300;
constexpr float DX = 10.0f, DT = 1e-3f, DT2 = DT * DT;

// tiling: 2 shots x 8x8 tiles -> 128 blocks
constexpr int NTY = 8, NTX = 8;
constexpr int TY = 22, TX = 34;              // nominal tile (last row/col smaller)
constexpr int NBLKS = S * NTY * NTX;         // 128
constexpr int THREADS = 768;                 // 1 cell/thread (748 cells max), 12 waves
constexpr int FSTR = 32;                     // flag stride: 1 flag per 128B line

constexpr int UW = TX + 17;                  // 51 (odd): u LDS row stride, 8-halo each side
constexpr int UH = TY + 16;                  // 38
constexpr int PYH = TY + 8;                  // 30: py rows [-4, rows+4), stride TX
constexpr int PXW = TX + 8;                  // 42: px cols [-4, cols+4), TY rows

// global staging strips (u only; py/px never exchanged)
constexpr int STRIDE_NS = 8 * TX;            // 272
constexpr int STRIDE_WE = TY * 8;            // 176
constexpr int STAGE_STRIDE = 2 * STRIDE_NS + 2 * STRIDE_WE;  // 896
constexpr int OFF_N = 0, OFF_S = STRIDE_NS;
constexpr int OFF_W = 2 * STRIDE_NS, OFF_E = 2 * STRIDE_NS + STRIDE_WE;

// stencil coefficients, offsets -4..4, pre-scaled by 1/dx^2 and 1/dx
__device__ __constant__ float C2D[9] = {
    (float)(-1.0/560.0/100.0), (float)(8.0/315.0/100.0), (float)(-1.0/5.0/100.0),
    (float)(8.0/5.0/100.0),    (float)(-205.0/72.0/100.0), (float)(8.0/5.0/100.0),
    (float)(-1.0/5.0/100.0),   (float)(8.0/315.0/100.0),  (float)(-1.0/560.0/100.0)};
__device__ __constant__ float C1D[9] = {
    (float)(1.0/280.0/10.0), (float)(-4.0/105.0/10.0), (float)(1.0/5.0/10.0),
    (float)(-4.0/5.0/10.0),  0.0f,                     (float)(4.0/5.0/10.0),
    (float)(-1.0/5.0/10.0),  (float)(4.0/105.0/10.0),  (float)(-1.0/280.0/10.0)};

// ---------------- agent-scope accessors (coherent at Infinity Cache) -------
__device__ __forceinline__ float gload(const float* p) {
    return __hip_atomic_load(p, __ATOMIC_RELAXED, __HIP_MEMORY_SCOPE_AGENT);
}
__device__ __forceinline__ void gstore(float* p, float v) {
    __hip_atomic_store(p, v, __ATOMIC_RELAXED, __HIP_MEMORY_SCOPE_AGENT);
}
__device__ __forceinline__ int iload(const int* p) {
    return __hip_atomic_load(p, __ATOMIC_RELAXED, __HIP_MEMORY_SCOPE_AGENT);
}
__device__ __forceinline__ void istore(int* p, int v) {
    __hip_atomic_store(p, v, __ATOMIC_RELAXED, __HIP_MEMORY_SCOPE_AGENT);
}

__device__ __forceinline__ float sigma_of(int d, int n, float smax) {
    float r = fmaxf(fmaxf((float)(PML - d) / (float)PML,
                          (float)(d - (n - 1 - PML)) / (float)PML), 0.0f);
    return smax * r * r;
}

// ---------------- setup: vmax -> sigma_max ----------------
__global__ void vmax_kernel(const float* __restrict__ vp, float* __restrict__ cst) {
    __shared__ float red[256];
    float m = 0.0f;
    for (int i = threadIdx.x; i < NY * NX; i += 256) m = fmaxf(m, vp[i]);
    red[threadIdx.x] = m;
    __syncthreads();
    for (int s2 = 128; s2 > 0; s2 >>= 1) {
        if (threadIdx.x < s2) red[threadIdx.x] = fmaxf(red[threadIdx.x], red[threadIdx.x + s2]);
        __syncthreads();
    }
    if (threadIdx.x == 0)
        cst[0] = 3.0f * red[0] * logf(1000.0f) / (2.0f * PML * DX);
}

// ------- persistent kernel: fully fused step (2 barriers), redundant CPML ---
__global__ __launch_bounds__(THREADS) void persist_kernel(
    const float* __restrict__ vp, const float* __restrict__ src,
    const int* __restrict__ src_loc, const int* __restrict__ rec_loc,
    float* __restrict__ out, float* __restrict__ stage,
    const float* __restrict__ cst, int* __restrict__ flags) {

    __shared__ float uS[2][UH * UW];       // u(t) / u(t-1)->u(t+1), swap each step
    __shared__ float pyS[2][PYH * TX];     // py double buffer (read old, write new)
    __shared__ float pxS[2][TY * PXW];     // px double buffer
    __shared__ float eS[TY * TX];          // dt^2 * v^2
    __shared__ float dS[TY * TX];          // 1/(1+0.5*s*dt)
    __shared__ float syS[TY], sxS[TX];
    __shared__ float byS[PYH], bymS[PYH], bxS[PXW], bxmS[PXW];

    const int tid = threadIdx.x;
    const int bid = blockIdx.x;
    const int sh  = bid / (NTY * NTX);
    const int tr  = bid - sh * (NTY * NTX);
    const int tyi = tr / NTX, txi = tr - tyi * NTX;
    const int y0 = tyi * TY, x0 = txi * TX;
    const int rows = min(TY, NYP - y0), cols = min(TX, NXP - x0);
    const float smax = cst[0];

    // zero LDS state (domain-boundary halos stay 0 forever)
    for (int i = tid; i < 2 * UH * UW; i += THREADS) ((float*)uS)[i] = 0.0f;
    for (int i = tid; i < 2 * PYH * TX; i += THREADS) ((float*)pyS)[i] = 0.0f;
    for (int i = tid; i < 2 * TY * PXW; i += THREADS) ((float*)pxS)[i] = 0.0f;

    if (tid < TY) syS[tid] = sigma_of(y0 + tid, NYP, smax);
    if (tid < TX) sxS[tid] = sigma_of(x0 + tid, NXP, smax);
    if (tid < PYH) {
        int yy = y0 - 4 + tid;
        if (yy >= 0 && yy < NYP) {
            float b = __expf(-sigma_of(yy, NYP, smax) * DT);
            byS[tid] = b; bymS[tid] = b - 1.0f;
        } else { byS[tid] = 0.0f; bymS[tid] = 0.0f; }
    }
    if (tid < PXW) {
        int xx = x0 - 4 + tid;
        if (xx >= 0 && xx < NXP) {
            float b = __expf(-sigma_of(xx, NXP, smax) * DT);
            bxS[tid] = b; bxmS[tid] = b - 1.0f;
        } else { bxS[tid] = 0.0f; bxmS[tid] = 0.0f; }
    }
    for (int i = tid; i < rows * cols; i += THREADS) {
        int rr = i / cols, cc = i - rr * cols;
        int gy = y0 + rr, gx = x0 + cc;
        int vy = min(max(gy - PML, 0), NY - 1), vx = min(max(gx - PML, 0), NX - 1);
        float v = vp[vy * NX + vx];
        eS[rr * TX + cc] = DT2 * v * v;
        float s_ = sigma_of(gy, NYP, smax) + sigma_of(gx, NXP, smax);
        dS[rr * TX + cc] = 1.0f / (1.0f + 0.5f * s_ * DT);
    }

    // source (NSRC == 1 per shot)
    const int sy = src_loc[sh * 2 + 0] + PML, sx = src_loc[sh * 2 + 1] + PML;
    const bool ownSrc = (sy >= y0 && sy < y0 + rows && sx >= x0 && sx < x0 + cols);
    const int sLy = sy - y0, sLx = sx - x0;
    const float* srcRow = src + sh * NT;

    // receiver: thread tid handles global receiver tid (<=1 per thread)
    int recLds = -1, recOut = 0;
    if (tid < S * NREC) {
        int rs = tid / NREC, rr2 = tid - rs * NREC;
        int ry = rec_loc[(rs * NREC + rr2) * 2 + 0] + PML;
        int rx = rec_loc[(rs * NREC + rr2) * 2 + 1] + PML;
        if (rs == sh && ry >= y0 && ry < y0 + rows && rx >= x0 && rx < x0 + cols) {
            recLds = (ry - y0 + 8) * UW + (rx - x0 + 8);
            recOut = rs * NT * NREC + rr2;
        }
    }

    const int bN = (tyi > 0)       ? bid - NTX : -1;
    const int bS = (tyi < NTY - 1) ? bid + NTX : -1;
    const int bW = (txi > 0)       ? bid - 1   : -1;
    const int bE = (txi < NTX - 1) ? bid + 1   : -1;

    const int nNS = 8 * cols, nWE = rows * 8;

    // per-thread cell (t-invariant): 1 cell per thread
    const bool hasTask = (tid < rows * cols);
    const int y = hasTask ? tid / cols : 0;
    const int x = hasTask ? tid - y * cols : 0;

    // per-wave poll assignment (lanes 0..3 watch N/S/W/E)
    const int lane = tid & 63;
    int pollNb = -1;
    if (lane == 0) pollNb = bN;
    else if (lane == 1) pollNb = bS;
    else if (lane == 2) pollNb = bW;
    else if (lane == 3) pollNb = bE;

    // prologue: stage pre-zeroed by host memset = u(0) strips; announce them.
    if (tid == 0) istore(&flags[bid * FSTR], 1);
    __syncthreads();

    int pa = 0, pb = 0;
    for (int t = 0; t < NT; t++) {
        const int par = t & 1;                 // slot holding u(t) strips
        float* uCur = uS[pa];
        float* uN   = uS[pa ^ 1];              // holds um; overwritten with un
        const float* pyO = pyS[pb];
        float*       pyN = pyS[pb ^ 1];
        const float* pxO = pxS[pb];
        float*       pxN = pxS[pb ^ 1];

        // ---- 1. per-wave neighbor poll (steady state: hits immediately) ----
        {
            bool done = (pollNb < 0);
            while (!__all(done ? 1 : 0)) {
                if (!done) done = (iload(&flags[pollNb * FSTR]) >= t + 1);
            }
        }

        // ---- 2. read neighbor strips (u(t)) into u halo ring, one task space
        {
            const int nTot = 2 * nNS + 2 * nWE;    // <= 896
            for (int i = tid; i < nTot; i += THREADS) {
                int j = i;
                if (j < nNS) {
                    if (bN >= 0) {
                        const float* nb = stage + (size_t)(bN * 2 + par) * STAGE_STRIDE + OFF_S;
                        int r2 = j / cols, c2 = j - r2 * cols;
                        uCur[r2 * UW + 8 + c2] = gload(nb + r2 * TX + c2);
                    }
                } else if ((j -= nNS) < nNS) {
                    if (bS >= 0) {
                        const float* nb = stage + (size_t)(bS * 2 + par) * STAGE_STRIDE + OFF_N;
                        int r2 = j / cols, c2 = j - r2 * cols;
                        uCur[(8 + rows + r2) * UW + 8 + c2] = gload(nb + r2 * TX + c2);
                    }
                } else if ((j -= nNS) < nWE) {
                    if (bW >= 0) {
                        const float* nb = stage + (size_t)(bW * 2 + par) * STAGE_STRIDE + OFF_E;
                        uCur[(8 + (j >> 3)) * UW + (j & 7)] = gload(nb + j);
                    }
                } else {
                    j -= nWE;
                    if (bE >= 0) {
                        const float* nb = stage + (size_t)(bE * 2 + par) * STAGE_STRIDE + OFF_W;
                        uCur[(8 + (j >> 3)) * UW + 8 + cols + (j & 7)] = gload(nb + j);
                    }
                }
            }
        }
        __syncthreads();                       // B2: halo complete

        // ---- 3. fused step: py'/px' (redundant, in registers) + un + push --
        float* sb = stage + (size_t)(bid * 2 + ((t + 1) & 1)) * STAGE_STRIDE;
        if (hasTask) {
            // u column y-8..y+8 at col x  (LDS row index = y+j, j=0..16)
            float uc[17];
#pragma unroll
            for (int j = 0; j < 17; j++) uc[j] = uCur[(y + j) * UW + 8 + x];
            // u row x-8..x+8 at row y    (LDS col index = x+k, k=0..16)
            float ur[17];
#pragma unroll
            for (int k = 0; k < 17; k++) ur[k] = uCur[(8 + y) * UW + x + k];

            // py_new at rows y-4..y+4 (j=0..8): by*py_old + (by-1)*d1y(u)
            float pyn[9];
#pragma unroll
            for (int j = 0; j < 9; j++) {
                float d1a = 0.0f, d1b = 0.0f;
#pragma unroll
                for (int k = 0; k < 4; k++) {
                    d1a = fmaf(C1D[k],     uc[j + k],     d1a);
                    d1b = fmaf(C1D[k + 5], uc[j + k + 5], d1b);
                }
                pyn[j] = fmaf(byS[y + j], pyO[(y + j) * TX + x],
                              bymS[y + j] * (d1a + d1b));
            }
            // px_new at cols x-4..x+4 (j=0..8)
            float pxn[9];
#pragma unroll
            for (int j = 0; j < 9; j++) {
                float d1a = 0.0f, d1b = 0.0f;
#pragma unroll
                for (int k = 0; k < 4; k++) {
                    d1a = fmaf(C1D[k],     ur[j + k],     d1a);
                    d1b = fmaf(C1D[k + 5], ur[j + k + 5], d1b);
                }
                pxn[j] = fmaf(bxS[x + j], pxO[y * PXW + x + j],
                              bxmS[x + j] * (d1a + d1b));
            }

            float d2y = 0.0f, d2x = 0.0f, d1py = 0.0f, d1px = 0.0f;
#pragma unroll
            for (int k = 0; k < 9; k++) {
                d2y = fmaf(C2D[k], uc[4 + k], d2y);
                d2x = fmaf(C2D[k], ur[4 + k], d2x);
                if (k != 4) {
                    d1py = fmaf(C1D[k], pyn[k], d1py);
                    d1px = fmaf(C1D[k], pxn[k], d1px);
                }
            }
            const float lap = (d2y + d2x) + (d1py + d1px);
            const float syv = syS[y], sxv = sxS[x];
            const float Av = 2.0f - syv * sxv * DT2;
            const float Bv = 1.0f - 0.5f * (syv + sxv) * DT;
            const float f = (ownSrc && y == sLy && x == sLx) ? srcRow[t] : 0.0f;
            const int ci = (8 + y) * UW + 8 + x;
            const float umv = uN[ci];
            const float unv = (Av * uc[8] - Bv * umv +
                               eS[y * TX + x] * (lap + f)) * dS[y * TX + x];
            uN[ci] = unv;

            // py/px LDS writes (own cell + apron rows/cols from redundant ends)
            pyN[(y + 4) * TX + x] = pyn[4];
            if (y < 4)         pyN[y * TX + x]       = pyn[0];
            if (y >= rows - 4) pyN[(y + 8) * TX + x] = pyn[8];
            pxN[y * PXW + (x + 4)] = pxn[4];
            if (x < 4)         pxN[y * PXW + x]       = pxn[0];
            if (x >= cols - 4) pxN[y * PXW + (x + 8)] = pxn[8];

            // fused strip push (u(t+1) ring cells, from register)
            if (y < 8)          gstore(sb + OFF_N + y * TX + x, unv);
            if (y >= rows - 8)  gstore(sb + OFF_S + (y - (rows - 8)) * TX + x, unv);
            if (x < 8)          gstore(sb + OFF_W + y * 8 + x, unv);
            if (x >= cols - 8)  gstore(sb + OFF_E + y * 8 + (x - (cols - 8)), unv);
        }
        __syncthreads();                       // B4: LDS visible + strip stores drained
        if (tid == 0 && t + 1 < NT) istore(&flags[bid * FSTR], t + 2);

        // ---- 4. receivers sample un ----
        if (recLds >= 0) out[recOut + t * NREC] = uN[recLds];

        pa ^= 1; pb ^= 1;
    }
}

// ---------------- host launch ----------------
extern "C" void kernel_launch(void* const* d_in, const int* in_sizes, int n_in,
                              void* d_out, int out_size, void* d_ws, size_t ws_size,
                              hipStream_t stream) {
    const float* vp = (const float*)d_in[0];
    const float* src = (const float*)d_in[1];
    const int* src_loc = (const int*)d_in[2];
    const int* rec_loc = (const int*)d_in[3];
    float* out = (float*)d_out;

    float* ws = (float*)d_ws;
    float* cst   = ws;                       // 16 floats
    int*   flags = (int*)(ws + 16);          // NBLKS * FSTR ints (padded flags)
    float* stage = ws + 16 + NBLKS * FSTR;   // NBLKS*2*STAGE_STRIDE floats

    // zero cst + flags + stage (stage zeros = u(0) border strips)
    hipMemsetAsync(d_ws, 0,
                   (size_t)(16 + NBLKS * FSTR + NBLKS * 2 * STAGE_STRIDE) * sizeof(float),
                   stream);
    vmax_kernel<<<1, 256, 0, stream>>>(vp, cst);
    persist_kernel<<<NBLKS, THREADS, 0, stream>>>(
        vp, src, src_loc, rec_loc, out, stage, cst, flags);
}

// Round 4
// 1170.500 us; speedup vs baseline: 1.7934x; 1.0701x over previous
//
#include <hip/hip_runtime.h>

// ---------------- problem constants ----------------
constexpr int NY = 100, NX = 200;
constexpr int PML = 35;
constexpr int NYP = 170, NXP = 270;          // padded grid
constexpr int S = 2, NREC = 100, NT = 300;
constexpr float DX = 10.0f, DT = 1e-3f, DT2 = DT * DT;

// tiling: 2 shots x 16x8 tiles -> 256 blocks (one per CU)
constexpr int NTY = 16, NTX = 8;
constexpr int TY = 11, TX = 34;              // nominal tile (last row/col smaller)
constexpr int NBLKS = S * NTY * NTX;         // 256
constexpr int THREADS = 384;                 // 1 cell/thread (374 cells max), 6 waves
constexpr int FSTR = 32;                     // flag stride: 1 flag per 128B line

constexpr int UW = TX + 17;                  // 51 (odd): u LDS row stride, 8-halo each side
constexpr int UH = TY + 16;                  // 27
constexpr int PYH = TY + 8;                  // 19: py rows [-4, rows+4), stride TX
constexpr int PXW = TX + 8;                  // 42: px cols [-4, cols+4), TY rows

// global staging strips (u only; py/px never exchanged)
constexpr int STRIDE_NS = 8 * TX;            // 272
constexpr int STRIDE_WE = TY * 8;            // 88
constexpr int STAGE_STRIDE = 2 * STRIDE_NS + 2 * STRIDE_WE;  // 720
constexpr int OFF_N = 0, OFF_S = STRIDE_NS;
constexpr int OFF_W = 2 * STRIDE_NS, OFF_E = 2 * STRIDE_NS + STRIDE_WE;

// stencil coefficients, offsets -4..4, pre-scaled by 1/dx^2 and 1/dx
__device__ __constant__ float C2D[9] = {
    (float)(-1.0/560.0/100.0), (float)(8.0/315.0/100.0), (float)(-1.0/5.0/100.0),
    (float)(8.0/5.0/100.0),    (float)(-205.0/72.0/100.0), (float)(8.0/5.0/100.0),
    (float)(-1.0/5.0/100.0),   (float)(8.0/315.0/100.0),  (float)(-1.0/560.0/100.0)};
__device__ __constant__ float C1D[9] = {
    (float)(1.0/280.0/10.0), (float)(-4.0/105.0/10.0), (float)(1.0/5.0/10.0),
    (float)(-4.0/5.0/10.0),  0.0f,                     (float)(4.0/5.0/10.0),
    (float)(-1.0/5.0/10.0),  (float)(4.0/105.0/10.0),  (float)(-1.0/280.0/10.0)};

// ---------------- agent-scope accessors (coherent at Infinity Cache) -------
__device__ __forceinline__ float gload(const float* p) {
    return __hip_atomic_load(p, __ATOMIC_RELAXED, __HIP_MEMORY_SCOPE_AGENT);
}
__device__ __forceinline__ void gstore(float* p, float v) {
    __hip_atomic_store(p, v, __ATOMIC_RELAXED, __HIP_MEMORY_SCOPE_AGENT);
}
__device__ __forceinline__ int iload(const int* p) {
    return __hip_atomic_load(p, __ATOMIC_RELAXED, __HIP_MEMORY_SCOPE_AGENT);
}
__device__ __forceinline__ void istore(int* p, int v) {
    __hip_atomic_store(p, v, __ATOMIC_RELAXED, __HIP_MEMORY_SCOPE_AGENT);
}

__device__ __forceinline__ float sigma_of(int d, int n, float smax) {
    float r = fmaxf(fmaxf((float)(PML - d) / (float)PML,
                          (float)(d - (n - 1 - PML)) / (float)PML), 0.0f);
    return smax * r * r;
}

// ---------------- setup: vmax -> sigma_max ----------------
__global__ void vmax_kernel(const float* __restrict__ vp, float* __restrict__ cst) {
    __shared__ float red[256];
    float m = 0.0f;
    for (int i = threadIdx.x; i < NY * NX; i += 256) m = fmaxf(m, vp[i]);
    red[threadIdx.x] = m;
    __syncthreads();
    for (int s2 = 128; s2 > 0; s2 >>= 1) {
        if (threadIdx.x < s2) red[threadIdx.x] = fmaxf(red[threadIdx.x], red[threadIdx.x + s2]);
        __syncthreads();
    }
    if (threadIdx.x == 0)
        cst[0] = 3.0f * red[0] * logf(1000.0f) / (2.0f * PML * DX);
}

// ------- persistent kernel: fully fused step (2 barriers), redundant CPML ---
__global__ __launch_bounds__(THREADS) void persist_kernel(
    const float* __restrict__ vp, const float* __restrict__ src,
    const int* __restrict__ src_loc, const int* __restrict__ rec_loc,
    float* __restrict__ out, float* __restrict__ stage,
    const float* __restrict__ cst, int* __restrict__ flags) {

    __shared__ float uS[2][UH * UW];       // u(t) / u(t-1)->u(t+1), swap each step
    __shared__ float pyS[2][PYH * TX];     // py double buffer (read old, write new)
    __shared__ float pxS[2][TY * PXW];     // px double buffer
    __shared__ float eS[TY * TX];          // dt^2 * v^2
    __shared__ float dS[TY * TX];          // 1/(1+0.5*s*dt)
    __shared__ float syS[TY], sxS[TX];
    __shared__ float byS[PYH], bymS[PYH], bxS[PXW], bxmS[PXW];

    const int tid = threadIdx.x;
    const int bid = blockIdx.x;
    const int sh  = bid / (NTY * NTX);
    const int tr  = bid - sh * (NTY * NTX);
    const int tyi = tr / NTX, txi = tr - tyi * NTX;
    const int y0 = tyi * TY, x0 = txi * TX;
    const int rows = min(TY, NYP - y0), cols = min(TX, NXP - x0);
    const float smax = cst[0];

    // zero LDS state (domain-boundary halos stay 0 forever)
    for (int i = tid; i < 2 * UH * UW; i += THREADS) ((float*)uS)[i] = 0.0f;
    for (int i = tid; i < 2 * PYH * TX; i += THREADS) ((float*)pyS)[i] = 0.0f;
    for (int i = tid; i < 2 * TY * PXW; i += THREADS) ((float*)pxS)[i] = 0.0f;

    if (tid < TY) syS[tid] = sigma_of(y0 + tid, NYP, smax);
    if (tid < TX) sxS[tid] = sigma_of(x0 + tid, NXP, smax);
    if (tid < PYH) {
        int yy = y0 - 4 + tid;
        if (yy >= 0 && yy < NYP) {
            float b = __expf(-sigma_of(yy, NYP, smax) * DT);
            byS[tid] = b; bymS[tid] = b - 1.0f;
        } else { byS[tid] = 0.0f; bymS[tid] = 0.0f; }
    }
    if (tid < PXW) {
        int xx = x0 - 4 + tid;
        if (xx >= 0 && xx < NXP) {
            float b = __expf(-sigma_of(xx, NXP, smax) * DT);
            bxS[tid] = b; bxmS[tid] = b - 1.0f;
        } else { bxS[tid] = 0.0f; bxmS[tid] = 0.0f; }
    }
    for (int i = tid; i < rows * cols; i += THREADS) {
        int rr = i / cols, cc = i - rr * cols;
        int gy = y0 + rr, gx = x0 + cc;
        int vy = min(max(gy - PML, 0), NY - 1), vx = min(max(gx - PML, 0), NX - 1);
        float v = vp[vy * NX + vx];
        eS[rr * TX + cc] = DT2 * v * v;
        float s_ = sigma_of(gy, NYP, smax) + sigma_of(gx, NXP, smax);
        dS[rr * TX + cc] = 1.0f / (1.0f + 0.5f * s_ * DT);
    }

    // source (NSRC == 1 per shot)
    const int sy = src_loc[sh * 2 + 0] + PML, sx = src_loc[sh * 2 + 1] + PML;
    const bool ownSrc = (sy >= y0 && sy < y0 + rows && sx >= x0 && sx < x0 + cols);
    const int sLy = sy - y0, sLx = sx - x0;
    const float* srcRow = src + sh * NT;

    // receiver: thread tid handles global receiver tid (<=1 per thread)
    int recLds = -1, recOut = 0;
    if (tid < S * NREC) {
        int rs = tid / NREC, rr2 = tid - rs * NREC;
        int ry = rec_loc[(rs * NREC + rr2) * 2 + 0] + PML;
        int rx = rec_loc[(rs * NREC + rr2) * 2 + 1] + PML;
        if (rs == sh && ry >= y0 && ry < y0 + rows && rx >= x0 && rx < x0 + cols) {
            recLds = (ry - y0 + 8) * UW + (rx - x0 + 8);
            recOut = rs * NT * NREC + rr2;
        }
    }

    const int bN = (tyi > 0)       ? bid - NTX : -1;
    const int bS = (tyi < NTY - 1) ? bid + NTX : -1;
    const int bW = (txi > 0)       ? bid - 1   : -1;
    const int bE = (txi < NTX - 1) ? bid + 1   : -1;

    const int nNS = 8 * cols, nWE = rows * 8;

    // per-thread cell (t-invariant): 1 cell per thread
    const bool hasTask = (tid < rows * cols);
    const int y = hasTask ? tid / cols : 0;
    const int x = hasTask ? tid - y * cols : 0;

    // per-wave poll assignment (lanes 0..3 watch N/S/W/E)
    const int lane = tid & 63;
    int pollNb = -1;
    if (lane == 0) pollNb = bN;
    else if (lane == 1) pollNb = bS;
    else if (lane == 2) pollNb = bW;
    else if (lane == 3) pollNb = bE;

    // prologue: stage pre-zeroed by host memset = u(0) strips; announce them.
    if (tid == 0) istore(&flags[bid * FSTR], 1);
    __syncthreads();

    int pa = 0, pb = 0;
    for (int t = 0; t < NT; t++) {
        const int par = t & 1;                 // slot holding u(t) strips
        float* uCur = uS[pa];
        float* uN   = uS[pa ^ 1];              // holds um; overwritten with un
        const float* pyO = pyS[pb];
        float*       pyN = pyS[pb ^ 1];
        const float* pxO = pxS[pb];
        float*       pxN = pxS[pb ^ 1];

        // ---- 1. per-wave neighbor poll (steady state: hits immediately) ----
        {
            bool done = (pollNb < 0);
            while (!__all(done ? 1 : 0)) {
                if (!done) done = (iload(&flags[pollNb * FSTR]) >= t + 1);
            }
        }

        // ---- 2. read neighbor strips (u(t)) into u halo ring, one task space
        {
            const int nTot = 2 * nNS + 2 * nWE;    // <= 720
            for (int i = tid; i < nTot; i += THREADS) {
                int j = i;
                if (j < nNS) {
                    if (bN >= 0) {
                        const float* nb = stage + (size_t)(bN * 2 + par) * STAGE_STRIDE + OFF_S;
                        int r2 = j / cols, c2 = j - r2 * cols;
                        uCur[r2 * UW + 8 + c2] = gload(nb + r2 * TX + c2);
                    }
                } else if ((j -= nNS) < nNS) {
                    if (bS >= 0) {
                        const float* nb = stage + (size_t)(bS * 2 + par) * STAGE_STRIDE + OFF_N;
                        int r2 = j / cols, c2 = j - r2 * cols;
                        uCur[(8 + rows + r2) * UW + 8 + c2] = gload(nb + r2 * TX + c2);
                    }
                } else if ((j -= nNS) < nWE) {
                    if (bW >= 0) {
                        const float* nb = stage + (size_t)(bW * 2 + par) * STAGE_STRIDE + OFF_E;
                        uCur[(8 + (j >> 3)) * UW + (j & 7)] = gload(nb + j);
                    }
                } else {
                    j -= nWE;
                    if (bE >= 0) {
                        const float* nb = stage + (size_t)(bE * 2 + par) * STAGE_STRIDE + OFF_W;
                        uCur[(8 + (j >> 3)) * UW + 8 + cols + (j & 7)] = gload(nb + j);
                    }
                }
            }
        }
        __syncthreads();                       // B2: halo complete

        // ---- 3. fused step: py'/px' (redundant, in registers) + un + push --
        float* sb = stage + (size_t)(bid * 2 + ((t + 1) & 1)) * STAGE_STRIDE;
        if (hasTask) {
            // u column y-8..y+8 at col x  (LDS row index = y+j, j=0..16)
            float uc[17];
#pragma unroll
            for (int j = 0; j < 17; j++) uc[j] = uCur[(y + j) * UW + 8 + x];
            // u row x-8..x+8 at row y    (LDS col index = x+k, k=0..16)
            float ur[17];
#pragma unroll
            for (int k = 0; k < 17; k++) ur[k] = uCur[(8 + y) * UW + x + k];

            // py_new at rows y-4..y+4 (j=0..8): by*py_old + (by-1)*d1y(u)
            float pyn[9];
#pragma unroll
            for (int j = 0; j < 9; j++) {
                float d1a = 0.0f, d1b = 0.0f;
#pragma unroll
                for (int k = 0; k < 4; k++) {
                    d1a = fmaf(C1D[k],     uc[j + k],     d1a);
                    d1b = fmaf(C1D[k + 5], uc[j + k + 5], d1b);
                }
                pyn[j] = fmaf(byS[y + j], pyO[(y + j) * TX + x],
                              bymS[y + j] * (d1a + d1b));
            }
            // px_new at cols x-4..x+4 (j=0..8)
            float pxn[9];
#pragma unroll
            for (int j = 0; j < 9; j++) {
                float d1a = 0.0f, d1b = 0.0f;
#pragma unroll
                for (int k = 0; k < 4; k++) {
                    d1a = fmaf(C1D[k],     ur[j + k],     d1a);
                    d1b = fmaf(C1D[k + 5], ur[j + k + 5], d1b);
                }
                pxn[j] = fmaf(bxS[x + j], pxO[y * PXW + x + j],
                              bxmS[x + j] * (d1a + d1b));
            }

            float d2y = 0.0f, d2x = 0.0f, d1py = 0.0f, d1px = 0.0f;
#pragma unroll
            for (int k = 0; k < 9; k++) {
                d2y = fmaf(C2D[k], uc[4 + k], d2y);
                d2x = fmaf(C2D[k], ur[4 + k], d2x);
                if (k != 4) {
                    d1py = fmaf(C1D[k], pyn[k], d1py);
                    d1px = fmaf(C1D[k], pxn[k], d1px);
                }
            }
            const float lap = (d2y + d2x) + (d1py + d1px);
            const float syv = syS[y], sxv = sxS[x];
            const float Av = 2.0f - syv * sxv * DT2;
            const float Bv = 1.0f - 0.5f * (syv + sxv) * DT;
            const float f = (ownSrc && y == sLy && x == sLx) ? srcRow[t] : 0.0f;
            const int ci = (8 + y) * UW + 8 + x;
            const float umv = uN[ci];
            const float unv = (Av * uc[8] - Bv * umv +
                               eS[y * TX + x] * (lap + f)) * dS[y * TX + x];
            uN[ci] = unv;

            // py/px LDS writes (own cell + apron rows/cols from redundant ends)
            pyN[(y + 4) * TX + x] = pyn[4];
            if (y < 4)         pyN[y * TX + x]       = pyn[0];
            if (y >= rows - 4) pyN[(y + 8) * TX + x] = pyn[8];
            pxN[y * PXW + (x + 4)] = pxn[4];
            if (x < 4)         pxN[y * PXW + x]       = pxn[0];
            if (x >= cols - 4) pxN[y * PXW + (x + 8)] = pxn[8];

            // fused strip push (u(t+1) ring cells, from register)
            if (y < 8)          gstore(sb + OFF_N + y * TX + x, unv);
            if (y >= rows - 8)  gstore(sb + OFF_S + (y - (rows - 8)) * TX + x, unv);
            if (x < 8)          gstore(sb + OFF_W + y * 8 + x, unv);
            if (x >= cols - 8)  gstore(sb + OFF_E + y * 8 + (x - (cols - 8)), unv);
        }
        __syncthreads();                       // B4: LDS visible + strip stores drained
        if (tid == 0 && t + 1 < NT) istore(&flags[bid * FSTR], t + 2);

        // ---- 4. receivers sample un ----
        if (recLds >= 0) out[recOut + t * NREC] = uN[recLds];

        pa ^= 1; pb ^= 1;
    }
}

// ---------------- host launch ----------------
extern "C" void kernel_launch(void* const* d_in, const int* in_sizes, int n_in,
                              void* d_out, int out_size, void* d_ws, size_t ws_size,
                              hipStream_t stream) {
    const float* vp = (const float*)d_in[0];
    const float* src = (const float*)d_in[1];
    const int* src_loc = (const int*)d_in[2];
    const int* rec_loc = (const int*)d_in[3];
    float* out = (float*)d_out;

    float* ws = (float*)d_ws;
    float* cst   = ws;                       // 16 floats
    int*   flags = (int*)(ws + 16);          // NBLKS * FSTR ints (padded flags)
    float* stage = ws + 16 + NBLKS * FSTR;   // NBLKS*2*STAGE_STRIDE floats

    // zero cst + flags + stage (stage zeros = u(0) border strips)
    hipMemsetAsync(d_ws, 0,
                   (size_t)(16 + NBLKS * FSTR + NBLKS * 2 * STAGE_STRIDE) * sizeof(float),
                   stream);
    vmax_kernel<<<1, 256, 0, stream>>>(vp, cst);
    persist_kernel<<<NBLKS, THREADS, 0, stream>>>(
        vp, src, src_loc, rec_loc, out, stage, cst, flags);
}

// Round 5
// 998.824 us; speedup vs baseline: 2.1017x; 1.1719x over previous
//
#include <hip/hip_runtime.h>

// ---------------- problem constants ----------------
constexpr int NY = 100, NX = 200;
constexpr int PML = 35;
constexpr int NYP = 170, NXP = 270;          // padded grid
constexpr int S = 2, NREC = 100, NT = 300;
constexpr float DX = 10.0f, DT = 1e-3f, DT2 = DT * DT;

// tiling: 2 shots x 16x8 tiles -> 256 blocks (one per CU)
constexpr int NTY = 16, NTX = 8;
constexpr int TY = 11, TX = 34;              // nominal tile (last row/col smaller)
constexpr int NBLKS = S * NTY * NTX;         // 256
constexpr int THREADS = 384;                 // 1 cell/thread (374 cells max), 6 waves

constexpr int UW = TX + 17;                  // 51 (odd): u LDS row stride, 8-halo each side
constexpr int UH = TY + 16;                  // 27
constexpr int PYH = TY + 8;                  // 19: py rows [-4, rows+4), stride TX
constexpr int PXW = TX + 8;                  // 42: px cols [-4, cols+4), TY rows

// seqlock strip layout: 128B lines = 31 data floats + 1 int tag
// N: 9 lines, S: 9 lines, W: 3 lines, E: 3 lines -> 24 lines / (block,parity)
constexpr int LD = 31;                       // data slots per line
constexpr int OFF_N = 0;                     // line-aligned float offsets
constexpr int OFF_S = 9 * 32;                // 288
constexpr int OFF_W = 18 * 32;               // 576
constexpr int OFF_E = 21 * 32;               // 672
constexpr int NLINES = 24;
constexpr int STAGE_STRIDE = NLINES * 32;    // 768 floats = 3072 B (128B-aligned)

// stencil coefficients, offsets -4..4, pre-scaled by 1/dx^2 and 1/dx
__device__ __constant__ float C2D[9] = {
    (float)(-1.0/560.0/100.0), (float)(8.0/315.0/100.0), (float)(-1.0/5.0/100.0),
    (float)(8.0/5.0/100.0),    (float)(-205.0/72.0/100.0), (float)(8.0/5.0/100.0),
    (float)(-1.0/5.0/100.0),   (float)(8.0/315.0/100.0),  (float)(-1.0/560.0/100.0)};
__device__ __constant__ float C1D[9] = {
    (float)(1.0/280.0/10.0), (float)(-4.0/105.0/10.0), (float)(1.0/5.0/10.0),
    (float)(-4.0/5.0/10.0),  0.0f,                     (float)(4.0/5.0/10.0),
    (float)(-1.0/5.0/10.0),  (float)(4.0/105.0/10.0),  (float)(-1.0/280.0/10.0)};

// ---------------- agent-scope accessors (coherent at Infinity Cache) -------
__device__ __forceinline__ float gload(const float* p) {
    return __hip_atomic_load(p, __ATOMIC_RELAXED, __HIP_MEMORY_SCOPE_AGENT);
}
__device__ __forceinline__ void gstore(float* p, float v) {
    __hip_atomic_store(p, v, __ATOMIC_RELAXED, __HIP_MEMORY_SCOPE_AGENT);
}
__device__ __forceinline__ int iload(const int* p) {
    return __hip_atomic_load(p, __ATOMIC_RELAXED, __HIP_MEMORY_SCOPE_AGENT);
}
__device__ __forceinline__ void istore(int* p, int v) {
    __hip_atomic_store(p, v, __ATOMIC_RELAXED, __HIP_MEMORY_SCOPE_AGENT);
}

__device__ __forceinline__ float sigma_of(int d, int n, float smax) {
    float r = fmaxf(fmaxf((float)(PML - d) / (float)PML,
                          (float)(d - (n - 1 - PML)) / (float)PML), 0.0f);
    return smax * r * r;
}

// ---------------- setup: vmax -> sigma_max ----------------
__global__ void vmax_kernel(const float* __restrict__ vp, float* __restrict__ cst) {
    __shared__ float red[256];
    float m = 0.0f;
    for (int i = threadIdx.x; i < NY * NX; i += 256) m = fmaxf(m, vp[i]);
    red[threadIdx.x] = m;
    __syncthreads();
    for (int s2 = 128; s2 > 0; s2 >>= 1) {
        if (threadIdx.x < s2) red[threadIdx.x] = fmaxf(red[threadIdx.x], red[threadIdx.x + s2]);
        __syncthreads();
    }
    if (threadIdx.x == 0)
        cst[0] = 3.0f * red[0] * logf(1000.0f) / (2.0f * PML * DX);
}

// ------- persistent kernel: fused step, seqlock line-tagged halo exchange ---
__global__ __launch_bounds__(THREADS) void persist_kernel(
    const float* __restrict__ vp, const float* __restrict__ src,
    const int* __restrict__ src_loc, const int* __restrict__ rec_loc,
    float* __restrict__ out, float* __restrict__ stage,
    const float* __restrict__ cst) {

    __shared__ float uS[2][UH * UW];       // u(t) / u(t-1)->u(t+1), swap each step
    __shared__ float pyS[2][PYH * TX];     // py double buffer (read old, write new)
    __shared__ float pxS[2][TY * PXW];     // px double buffer
    __shared__ float eS[TY * TX];          // dt^2 * v^2
    __shared__ float dS[TY * TX];          // 1/(1+0.5*s*dt)
    __shared__ float syS[TY], sxS[TX];
    __shared__ float byS[PYH], bymS[PYH], bxS[PXW], bxmS[PXW];

    const int tid = threadIdx.x;
    const int bid = blockIdx.x;
    const int sh  = bid / (NTY * NTX);
    const int tr  = bid - sh * (NTY * NTX);
    const int tyi = tr / NTX, txi = tr - tyi * NTX;
    const int y0 = tyi * TY, x0 = txi * TX;
    const int rows = min(TY, NYP - y0), cols = min(TX, NXP - x0);
    const float smax = cst[0];

    // zero LDS state (domain-boundary halos stay 0 forever)
    for (int i = tid; i < 2 * UH * UW; i += THREADS) ((float*)uS)[i] = 0.0f;
    for (int i = tid; i < 2 * PYH * TX; i += THREADS) ((float*)pyS)[i] = 0.0f;
    for (int i = tid; i < 2 * TY * PXW; i += THREADS) ((float*)pxS)[i] = 0.0f;

    if (tid < TY) syS[tid] = sigma_of(y0 + tid, NYP, smax);
    if (tid < TX) sxS[tid] = sigma_of(x0 + tid, NXP, smax);
    if (tid < PYH) {
        int yy = y0 - 4 + tid;
        if (yy >= 0 && yy < NYP) {
            float b = __expf(-sigma_of(yy, NYP, smax) * DT);
            byS[tid] = b; bymS[tid] = b - 1.0f;
        } else { byS[tid] = 0.0f; bymS[tid] = 0.0f; }
    }
    if (tid < PXW) {
        int xx = x0 - 4 + tid;
        if (xx >= 0 && xx < NXP) {
            float b = __expf(-sigma_of(xx, NXP, smax) * DT);
            bxS[tid] = b; bxmS[tid] = b - 1.0f;
        } else { bxS[tid] = 0.0f; bxmS[tid] = 0.0f; }
    }
    for (int i = tid; i < rows * cols; i += THREADS) {
        int rr = i / cols, cc = i - rr * cols;
        int gy = y0 + rr, gx = x0 + cc;
        int vy = min(max(gy - PML, 0), NY - 1), vx = min(max(gx - PML, 0), NX - 1);
        float v = vp[vy * NX + vx];
        eS[rr * TX + cc] = DT2 * v * v;
        float s_ = sigma_of(gy, NYP, smax) + sigma_of(gx, NXP, smax);
        dS[rr * TX + cc] = 1.0f / (1.0f + 0.5f * s_ * DT);
    }

    // source (NSRC == 1 per shot)
    const int sy = src_loc[sh * 2 + 0] + PML, sx = src_loc[sh * 2 + 1] + PML;
    const bool ownSrc = (sy >= y0 && sy < y0 + rows && sx >= x0 && sx < x0 + cols);
    const int sLy = sy - y0, sLx = sx - x0;
    const float* srcRow = src + sh * NT;

    // receiver: thread tid handles global receiver tid (<=1 per thread)
    int recLds = -1, recOut = 0;
    if (tid < S * NREC) {
        int rs = tid / NREC, rr2 = tid - rs * NREC;
        int ry = rec_loc[(rs * NREC + rr2) * 2 + 0] + PML;
        int rx = rec_loc[(rs * NREC + rr2) * 2 + 1] + PML;
        if (rs == sh && ry >= y0 && ry < y0 + rows && rx >= x0 && rx < x0 + cols) {
            recLds = (ry - y0 + 8) * UW + (rx - x0 + 8);
            recOut = rs * NT * NREC + rr2;
        }
    }

    const int bN = (tyi > 0)       ? bid - NTX : -1;
    const int bS = (tyi < NTY - 1) ? bid + NTX : -1;
    const int bW = (txi > 0)       ? bid - 1   : -1;
    const int bE = (txi < NTX - 1) ? bid + 1   : -1;

    const int nNS = 8 * cols, nWE = rows * 8;
    const int nTot = 2 * nNS + 2 * nWE;       // <= 720 <= 2*THREADS

    // ---- precompute the 2 halo-read descriptors per thread (t-invariant) ----
    int hLds[2]  = {-1, -1};    // LDS dest index
    int hLine[2] = {0, 0};      // float offset of source line base (w/o parity)
    int hSlot[2] = {0, 0};      // data slot within line
#pragma unroll
    for (int e = 0; e < 2; e++) {
        int i = tid + e * THREADS;
        if (i >= nTot) continue;
        int j = i, nb = -1, base = 0, o = 0, lds = -1;
        if (j < nNS) {
            nb = bN; base = OFF_S;
            int r2 = j / cols, c2 = j - r2 * cols;
            o = r2 * TX + c2; lds = r2 * UW + 8 + c2;
        } else if ((j -= nNS) < nNS) {
            nb = bS; base = OFF_N;
            int r2 = j / cols, c2 = j - r2 * cols;
            o = r2 * TX + c2; lds = (8 + rows + r2) * UW + 8 + c2;
        } else if ((j -= nNS) < nWE) {
            nb = bW; base = OFF_E;
            o = j; lds = (8 + (j >> 3)) * UW + (j & 7);
        } else {
            j -= nWE;
            nb = bE; base = OFF_W;
            o = j; lds = (8 + (j >> 3)) * UW + 8 + cols + (j & 7);
        }
        if (nb < 0) continue;
        int line = o / LD, slot = o - line * LD;
        hLds[e]  = lds;
        hLine[e] = nb * 2 * STAGE_STRIDE + base + line * 32;
        hSlot[e] = slot;
    }

    // ---- precompute strip-push addresses for own cell (t-invariant) ----
    const bool hasTask = (tid < rows * cols);
    const int y = hasTask ? tid / cols : 0;
    const int x = hasTask ? tid - y * cols : 0;
    int aN = -1, aS = -1, aW = -1, aE = -1;
    if (hasTask) {
        if (y < 8)          { int o = y * TX + x;               aN = OFF_N + (o / LD) * 32 + o % LD; }
        if (y >= rows - 8)  { int o = (y - (rows - 8)) * TX + x; aS = OFF_S + (o / LD) * 32 + o % LD; }
        if (x < 8)          { int o = y * 8 + x;                aW = OFF_W + (o / LD) * 32 + o % LD; }
        if (x >= cols - 8)  { int o = y * 8 + (x - (cols - 8)); aE = OFF_E + (o / LD) * 32 + o % LD; }
    }

    // prologue: publish tags=1 on parity-0 slot (data = zeros from host memset)
    if (tid < NLINES)
        istore((int*)(stage + (size_t)(bid * 2 + 0) * STAGE_STRIDE + tid * 32 + 31), 1);
    __syncthreads();

    int pa = 0, pb = 0;
    for (int t = 0; t < NT; t++) {
        const int par = t & 1;                 // slot holding u(t) strips
        float* uCur = uS[pa];
        float* uN   = uS[pa ^ 1];              // holds um; overwritten with un
        const float* pyO = pyS[pb];
        float*       pyN = pyS[pb ^ 1];
        const float* pxO = pxS[pb];
        float*       pxN = pxS[pb ^ 1];

        // ---- 1. seqlock halo read: spin on (data,tag) from the same line ----
#pragma unroll
        for (int e = 0; e < 2; e++) {
            if (hLds[e] >= 0) {
                const float* lp = stage + hLine[e] + par * STAGE_STRIDE;
                float v; int tg;
                do {
                    v  = gload(lp + hSlot[e]);
                    tg = iload((const int*)(lp + 31));
                } while (tg < t + 1);
                uCur[hLds[e]] = v;
            }
        }
        __syncthreads();                       // B2: halo complete

        // ---- 2. fused step: py'/px' (redundant, in registers) + un + push --
        float* sb = stage + (size_t)(bid * 2 + ((t + 1) & 1)) * STAGE_STRIDE;
        if (hasTask) {
            // u column y-8..y+8 at col x  (LDS row index = y+j, j=0..16)
            float uc[17];
#pragma unroll
            for (int j = 0; j < 17; j++) uc[j] = uCur[(y + j) * UW + 8 + x];
            // u row x-8..x+8 at row y    (LDS col index = x+k, k=0..16)
            float ur[17];
#pragma unroll
            for (int k = 0; k < 17; k++) ur[k] = uCur[(8 + y) * UW + x + k];

            // py_new at rows y-4..y+4 (j=0..8): by*py_old + (by-1)*d1y(u)
            float pyn[9];
#pragma unroll
            for (int j = 0; j < 9; j++) {
                float d1a = 0.0f, d1b = 0.0f;
#pragma unroll
                for (int k = 0; k < 4; k++) {
                    d1a = fmaf(C1D[k],     uc[j + k],     d1a);
                    d1b = fmaf(C1D[k + 5], uc[j + k + 5], d1b);
                }
                pyn[j] = fmaf(byS[y + j], pyO[(y + j) * TX + x],
                              bymS[y + j] * (d1a + d1b));
            }
            // px_new at cols x-4..x+4 (j=0..8)
            float pxn[9];
#pragma unroll
            for (int j = 0; j < 9; j++) {
                float d1a = 0.0f, d1b = 0.0f;
#pragma unroll
                for (int k = 0; k < 4; k++) {
                    d1a = fmaf(C1D[k],     ur[j + k],     d1a);
                    d1b = fmaf(C1D[k + 5], ur[j + k + 5], d1b);
                }
                pxn[j] = fmaf(bxS[x + j], pxO[y * PXW + x + j],
                              bxmS[x + j] * (d1a + d1b));
            }

            float d2y = 0.0f, d2x = 0.0f, d1py = 0.0f, d1px = 0.0f;
#pragma unroll
            for (int k = 0; k < 9; k++) {
                d2y = fmaf(C2D[k], uc[4 + k], d2y);
                d2x = fmaf(C2D[k], ur[4 + k], d2x);
                if (k != 4) {
                    d1py = fmaf(C1D[k], pyn[k], d1py);
                    d1px = fmaf(C1D[k], pxn[k], d1px);
                }
            }
            const float lap = (d2y + d2x) + (d1py + d1px);
            const float syv = syS[y], sxv = sxS[x];
            const float Av = 2.0f - syv * sxv * DT2;
            const float Bv = 1.0f - 0.5f * (syv + sxv) * DT;
            const float f = (ownSrc && y == sLy && x == sLx) ? srcRow[t] : 0.0f;
            const int ci = (8 + y) * UW + 8 + x;
            const float umv = uN[ci];
            const float unv = (Av * uc[8] - Bv * umv +
                               eS[y * TX + x] * (lap + f)) * dS[y * TX + x];
            uN[ci] = unv;

            // py/px LDS writes (own cell + apron rows/cols from redundant ends)
            pyN[(y + 4) * TX + x] = pyn[4];
            if (y < 4)         pyN[y * TX + x]       = pyn[0];
            if (y >= rows - 4) pyN[(y + 8) * TX + x] = pyn[8];
            pxN[y * PXW + (x + 4)] = pxn[4];
            if (x < 4)         pxN[y * PXW + x]       = pxn[0];
            if (x >= cols - 4) pxN[y * PXW + (x + 8)] = pxn[8];

            // fused strip push (u(t+1) ring cells, from register)
            if (aN >= 0) gstore(sb + aN, unv);
            if (aS >= 0) gstore(sb + aS, unv);
            if (aW >= 0) gstore(sb + aW, unv);
            if (aE >= 0) gstore(sb + aE, unv);
        }
        __syncthreads();           // B4: LDS visible + strip data stores drained

        // ---- 3. publish tags for the slot just written ----
        if (tid < NLINES)
            istore((int*)(sb + tid * 32 + 31), t + 2);

        // ---- 4. receivers sample un ----
        if (recLds >= 0) out[recOut + t * NREC] = uN[recLds];

        pa ^= 1; pb ^= 1;
    }
}

// ---------------- host launch ----------------
extern "C" void kernel_launch(void* const* d_in, const int* in_sizes, int n_in,
                              void* d_out, int out_size, void* d_ws, size_t ws_size,
                              hipStream_t stream) {
    const float* vp = (const float*)d_in[0];
    const float* src = (const float*)d_in[1];
    const int* src_loc = (const int*)d_in[2];
    const int* rec_loc = (const int*)d_in[3];
    float* out = (float*)d_out;

    float* ws = (float*)d_ws;
    float* cst   = ws;                       // 32 floats (keeps stage 128B-aligned)
    float* stage = ws + 32;                  // NBLKS*2*STAGE_STRIDE floats

    // zero cst + stage (stage zeros = u(0) border strips; tags published by kernel)
    hipMemsetAsync(d_ws, 0,
                   (size_t)(32 + NBLKS * 2 * STAGE_STRIDE) * sizeof(float),
                   stream);
    vmax_kernel<<<1, 256, 0, stream>>>(vp, cst);
    persist_kernel<<<NBLKS, THREADS, 0, stream>>>(
        vp, src, src_loc, rec_loc, out, stage, cst);
}

// Round 6
// 815.098 us; speedup vs baseline: 2.5754x; 1.2254x over previous
//
#include <hip/hip_runtime.h>

// ---------------- problem constants ----------------
constexpr int NY = 100, NX = 200;
constexpr int PML = 35;
constexpr int NYP = 170, NXP = 270;          // padded grid
constexpr int S = 2, NREC = 100, NT = 300;
constexpr float DX = 10.0f, DT = 1e-3f, DT2 = DT * DT;

// tiling: 2 shots x 16x8 tiles -> 256 blocks (one per CU)
constexpr int NTY = 16, NTX = 8;
constexpr int TY = 11, TX = 34;              // nominal tile (last row/col smaller)
constexpr int NBLKS = S * NTY * NTX;         // 256
constexpr int THREADS = 384;                 // 1 cell/thread (374 cells max), 6 waves

constexpr int UW = TX + 17;                  // 51 (odd): u LDS row stride, 8-halo each side
constexpr int UH = TY + 16;                  // 27
constexpr int PYH = TY + 8;                  // 19: py rows [-4, rows+4), stride TX
constexpr int PXW = TX + 8;                  // 42: px cols [-4, cols+4), TY rows

// packed strips: each halo cell is 8B {float value, int tag} (single-copy atomic)
constexpr int CELLS_NS = 8 * TX;             // 272
constexpr int CELLS_WE = TY * 8;             // 88
constexpr int OFF_N = 0;
constexpr int OFF_S = CELLS_NS;              // 272
constexpr int OFF_W = 2 * CELLS_NS;          // 544
constexpr int OFF_E = 2 * CELLS_NS + CELLS_WE;  // 632
constexpr int STAGE_CELLS = 2 * CELLS_NS + 2 * CELLS_WE;  // 720 cells = 5760 B

typedef unsigned long long u64;

// stencil coefficients, offsets -4..4, pre-scaled by 1/dx^2 and 1/dx
__device__ __constant__ float C2D[9] = {
    (float)(-1.0/560.0/100.0), (float)(8.0/315.0/100.0), (float)(-1.0/5.0/100.0),
    (float)(8.0/5.0/100.0),    (float)(-205.0/72.0/100.0), (float)(8.0/5.0/100.0),
    (float)(-1.0/5.0/100.0),   (float)(8.0/315.0/100.0),  (float)(-1.0/560.0/100.0)};
__device__ __constant__ float C1D[9] = {
    (float)(1.0/280.0/10.0), (float)(-4.0/105.0/10.0), (float)(1.0/5.0/10.0),
    (float)(-4.0/5.0/10.0),  0.0f,                     (float)(4.0/5.0/10.0),
    (float)(-1.0/5.0/10.0),  (float)(4.0/105.0/10.0),  (float)(-1.0/280.0/10.0)};

// ---------------- agent-scope accessors (coherent at Infinity Cache) -------
__device__ __forceinline__ u64 gload64(const u64* p) {
    return __hip_atomic_load(p, __ATOMIC_RELAXED, __HIP_MEMORY_SCOPE_AGENT);
}
__device__ __forceinline__ void gstore64(u64* p, u64 v) {
    __hip_atomic_store(p, v, __ATOMIC_RELAXED, __HIP_MEMORY_SCOPE_AGENT);
}

__device__ __forceinline__ float sigma_of(int d, int n, float smax) {
    float r = fmaxf(fmaxf((float)(PML - d) / (float)PML,
                          (float)(d - (n - 1 - PML)) / (float)PML), 0.0f);
    return smax * r * r;
}

// ---------------- setup: vmax -> sigma_max ----------------
__global__ void vmax_kernel(const float* __restrict__ vp, float* __restrict__ cst) {
    __shared__ float red[256];
    float m = 0.0f;
    for (int i = threadIdx.x; i < NY * NX; i += 256) m = fmaxf(m, vp[i]);
    red[threadIdx.x] = m;
    __syncthreads();
    for (int s2 = 128; s2 > 0; s2 >>= 1) {
        if (threadIdx.x < s2) red[threadIdx.x] = fmaxf(red[threadIdx.x], red[threadIdx.x + s2]);
        __syncthreads();
    }
    if (threadIdx.x == 0)
        cst[0] = 3.0f * red[0] * logf(1000.0f) / (2.0f * PML * DX);
}

// ------- persistent kernel: fused step, per-cell packed {value,tag} strips --
__global__ __launch_bounds__(THREADS) void persist_kernel(
    const float* __restrict__ vp, const float* __restrict__ src,
    const int* __restrict__ src_loc, const int* __restrict__ rec_loc,
    float* __restrict__ out, u64* __restrict__ stage,
    const float* __restrict__ cst) {

    __shared__ float uS[2][UH * UW];       // u(t) / u(t-1)->u(t+1), swap each step
    __shared__ float pyS[2][PYH * TX];     // py double buffer (read old, write new)
    __shared__ float pxS[2][TY * PXW];     // px double buffer
    __shared__ float eS[TY * TX];          // dt^2 * v^2
    __shared__ float dS[TY * TX];          // 1/(1+0.5*s*dt)
    __shared__ float syS[TY], sxS[TX];
    __shared__ float byS[PYH], bymS[PYH], bxS[PXW], bxmS[PXW];

    const int tid = threadIdx.x;
    const int bid = blockIdx.x;
    const int sh  = bid / (NTY * NTX);
    const int tr  = bid - sh * (NTY * NTX);
    const int tyi = tr / NTX, txi = tr - tyi * NTX;
    const int y0 = tyi * TY, x0 = txi * TX;
    const int rows = min(TY, NYP - y0), cols = min(TX, NXP - x0);
    const float smax = cst[0];

    // zero LDS state (domain-boundary halos stay 0 forever)
    for (int i = tid; i < 2 * UH * UW; i += THREADS) ((float*)uS)[i] = 0.0f;
    for (int i = tid; i < 2 * PYH * TX; i += THREADS) ((float*)pyS)[i] = 0.0f;
    for (int i = tid; i < 2 * TY * PXW; i += THREADS) ((float*)pxS)[i] = 0.0f;

    if (tid < TY) syS[tid] = sigma_of(y0 + tid, NYP, smax);
    if (tid < TX) sxS[tid] = sigma_of(x0 + tid, NXP, smax);
    if (tid < PYH) {
        int yy = y0 - 4 + tid;
        if (yy >= 0 && yy < NYP) {
            float b = __expf(-sigma_of(yy, NYP, smax) * DT);
            byS[tid] = b; bymS[tid] = b - 1.0f;
        } else { byS[tid] = 0.0f; bymS[tid] = 0.0f; }
    }
    if (tid < PXW) {
        int xx = x0 - 4 + tid;
        if (xx >= 0 && xx < NXP) {
            float b = __expf(-sigma_of(xx, NXP, smax) * DT);
            bxS[tid] = b; bxmS[tid] = b - 1.0f;
        } else { bxS[tid] = 0.0f; bxmS[tid] = 0.0f; }
    }
    for (int i = tid; i < rows * cols; i += THREADS) {
        int rr = i / cols, cc = i - rr * cols;
        int gy = y0 + rr, gx = x0 + cc;
        int vy = min(max(gy - PML, 0), NY - 1), vx = min(max(gx - PML, 0), NX - 1);
        float v = vp[vy * NX + vx];
        eS[rr * TX + cc] = DT2 * v * v;
        float s_ = sigma_of(gy, NYP, smax) + sigma_of(gx, NXP, smax);
        dS[rr * TX + cc] = 1.0f / (1.0f + 0.5f * s_ * DT);
    }

    // source (NSRC == 1 per shot)
    const int sy = src_loc[sh * 2 + 0] + PML, sx = src_loc[sh * 2 + 1] + PML;
    const bool ownSrc = (sy >= y0 && sy < y0 + rows && sx >= x0 && sx < x0 + cols);
    const int sLy = sy - y0, sLx = sx - x0;
    const float* srcRow = src + sh * NT;

    // receiver: thread tid handles global receiver tid (<=1 per thread)
    int recLds = -1, recOut = 0;
    if (tid < S * NREC) {
        int rs = tid / NREC, rr2 = tid - rs * NREC;
        int ry = rec_loc[(rs * NREC + rr2) * 2 + 0] + PML;
        int rx = rec_loc[(rs * NREC + rr2) * 2 + 1] + PML;
        if (rs == sh && ry >= y0 && ry < y0 + rows && rx >= x0 && rx < x0 + cols) {
            recLds = (ry - y0 + 8) * UW + (rx - x0 + 8);
            recOut = rs * NT * NREC + rr2;
        }
    }

    const int bN = (tyi > 0)       ? bid - NTX : -1;
    const int bS = (tyi < NTY - 1) ? bid + NTX : -1;
    const int bW = (txi > 0)       ? bid - 1   : -1;
    const int bE = (txi < NTX - 1) ? bid + 1   : -1;

    const int nNS = 8 * cols, nWE = rows * 8;
    const int nTot = 2 * nNS + 2 * nWE;       // <= 720 <= 2*THREADS

    // ---- precompute the 2 halo-read descriptors per thread (t-invariant) ----
    // skip cells beyond the neighbor's domain (they stay 0 in LDS, as reference)
    int hLds[2]  = {-1, -1};    // LDS dest index
    int hSrc[2]  = {0, 0};      // cell index in stage (w/o parity term)
#pragma unroll
    for (int e = 0; e < 2; e++) {
        int i = tid + e * THREADS;
        if (i >= nTot) continue;
        int j = i, nb = -1, o = 0, lds = -1;
        if (j < nNS) {                         // from N neighbor's S strip
            nb = bN;
            int r2 = j / cols, c2 = j - r2 * cols;
            o = OFF_S + r2 * TX + c2;          // N nb always has rows==TY>=8
            lds = r2 * UW + 8 + c2;
        } else if ((j -= nNS) < nNS) {         // from S neighbor's N strip
            nb = bS;
            int r2 = j / cols, c2 = j - r2 * cols;
            if (nb >= 0) {
                int rowsS = min(TY, NYP - (y0 + TY));  // S nb row count
                if (r2 >= rowsS) nb = -1;      // out-of-domain: stays 0
            }
            o = OFF_N + r2 * TX + c2;
            lds = (8 + rows + r2) * UW + 8 + c2;
        } else if ((j -= nNS) < nWE) {         // from W neighbor's E strip
            nb = bW;
            o = OFF_E + j;
            lds = (8 + (j >> 3)) * UW + (j & 7);
        } else {                               // from E neighbor's W strip
            j -= nWE;
            nb = bE;
            o = OFF_W + j;
            lds = (8 + (j >> 3)) * UW + 8 + cols + (j & 7);
        }
        if (nb < 0) continue;
        hLds[e] = lds;
        hSrc[e] = nb * 2 * STAGE_CELLS + o;
    }

    // ---- precompute strip-push cell offsets for own cell (t-invariant) ----
    const bool hasTask = (tid < rows * cols);
    const int y = hasTask ? tid / cols : 0;
    const int x = hasTask ? tid - y * cols : 0;
    int aN = -1, aS = -1, aW = -1, aE = -1;
    if (hasTask) {
        if (y < 8)          aN = OFF_N + y * TX + x;
        if (y >= rows - 8)  aS = OFF_S + (y - (rows - 8)) * TX + x;
        if (x < 8)          aW = OFF_W + y * 8 + x;
        if (x >= cols - 8)  aE = OFF_E + y * 8 + (x - (cols - 8));
    }

    // prologue: publish u(0)=0 cells with tag=1 into parity-0 slot
    {
        const u64 PK0 = ((u64)1 << 32);        // value bits 0.0f, tag 1
        u64* s0 = stage + (size_t)(bid * 2 + 0) * STAGE_CELLS;
        if (hasTask) {
            if (aN >= 0) gstore64(s0 + aN, PK0);
            if (aS >= 0) gstore64(s0 + aS, PK0);
            if (aW >= 0) gstore64(s0 + aW, PK0);
            if (aE >= 0) gstore64(s0 + aE, PK0);
        }
    }
    __syncthreads();

    int pa = 0, pb = 0;
    for (int t = 0; t < NT; t++) {
        const int par = t & 1;                 // slot holding u(t) strips
        float* uCur = uS[pa];
        float* uN   = uS[pa ^ 1];              // holds um; overwritten with un
        const float* pyO = pyS[pb];
        float*       pyN = pyS[pb ^ 1];
        const float* pxO = pxS[pb];
        float*       pxN = pxS[pb ^ 1];

        // ---- 1. packed halo read: one 8B atomic load per cell (race-free) ---
        {
            const bool n0 = (hLds[0] >= 0), n1 = (hLds[1] >= 0);
            const u64* s0 = stage + (size_t)par * STAGE_CELLS + hSrc[0];
            const u64* s1 = stage + (size_t)par * STAGE_CELLS + hSrc[1];
            u64 p0 = 0, p1 = 0;
            if (n0) p0 = gload64(s0);          // both loads in flight (1 RT)
            if (n1) p1 = gload64(s1);
            for (;;) {
                bool ok0 = !n0 || (int)(p0 >> 32) >= t + 1;
                bool ok1 = !n1 || (int)(p1 >> 32) >= t + 1;
                if (ok0 && ok1) break;
                if (!ok0) p0 = gload64(s0);
                if (!ok1) p1 = gload64(s1);
            }
            if (n0) uCur[hLds[0]] = __uint_as_float((unsigned)p0);
            if (n1) uCur[hLds[1]] = __uint_as_float((unsigned)p1);
        }
        __syncthreads();                       // B2: halo complete

        // ---- 2. fused step: py'/px' (redundant, in registers) + un + push --
        u64* sb = stage + (size_t)(bid * 2 + ((t + 1) & 1)) * STAGE_CELLS;
        if (hasTask) {
            // u column y-8..y+8 at col x  (LDS row index = y+j, j=0..16)
            float uc[17];
#pragma unroll
            for (int j = 0; j < 17; j++) uc[j] = uCur[(y + j) * UW + 8 + x];
            // u row x-8..x+8 at row y    (LDS col index = x+k, k=0..16)
            float ur[17];
#pragma unroll
            for (int k = 0; k < 17; k++) ur[k] = uCur[(8 + y) * UW + x + k];

            // py_new at rows y-4..y+4 (j=0..8): by*py_old + (by-1)*d1y(u)
            float pyn[9];
#pragma unroll
            for (int j = 0; j < 9; j++) {
                float d1a = 0.0f, d1b = 0.0f;
#pragma unroll
                for (int k = 0; k < 4; k++) {
                    d1a = fmaf(C1D[k],     uc[j + k],     d1a);
                    d1b = fmaf(C1D[k + 5], uc[j + k + 5], d1b);
                }
                pyn[j] = fmaf(byS[y + j], pyO[(y + j) * TX + x],
                              bymS[y + j] * (d1a + d1b));
            }
            // px_new at cols x-4..x+4 (j=0..8)
            float pxn[9];
#pragma unroll
            for (int j = 0; j < 9; j++) {
                float d1a = 0.0f, d1b = 0.0f;
#pragma unroll
                for (int k = 0; k < 4; k++) {
                    d1a = fmaf(C1D[k],     ur[j + k],     d1a);
                    d1b = fmaf(C1D[k + 5], ur[j + k + 5], d1b);
                }
                pxn[j] = fmaf(bxS[x + j], pxO[y * PXW + x + j],
                              bxmS[x + j] * (d1a + d1b));
            }

            float d2y = 0.0f, d2x = 0.0f, d1py = 0.0f, d1px = 0.0f;
#pragma unroll
            for (int k = 0; k < 9; k++) {
                d2y = fmaf(C2D[k], uc[4 + k], d2y);
                d2x = fmaf(C2D[k], ur[4 + k], d2x);
                if (k != 4) {
                    d1py = fmaf(C1D[k], pyn[k], d1py);
                    d1px = fmaf(C1D[k], pxn[k], d1px);
                }
            }
            const float lap = (d2y + d2x) + (d1py + d1px);
            const float syv = syS[y], sxv = sxS[x];
            const float Av = 2.0f - syv * sxv * DT2;
            const float Bv = 1.0f - 0.5f * (syv + sxv) * DT;
            const float f = (ownSrc && y == sLy && x == sLx) ? srcRow[t] : 0.0f;
            const int ci = (8 + y) * UW + 8 + x;
            const float umv = uN[ci];
            const float unv = (Av * uc[8] - Bv * umv +
                               eS[y * TX + x] * (lap + f)) * dS[y * TX + x];
            uN[ci] = unv;

            // py/px LDS writes (own cell + apron rows/cols from redundant ends)
            pyN[(y + 4) * TX + x] = pyn[4];
            if (y < 4)         pyN[y * TX + x]       = pyn[0];
            if (y >= rows - 4) pyN[(y + 8) * TX + x] = pyn[8];
            pxN[y * PXW + (x + 4)] = pxn[4];
            if (x < 4)         pxN[y * PXW + x]       = pxn[0];
            if (x >= cols - 4) pxN[y * PXW + (x + 8)] = pxn[8];

            // fused packed publish: {u(t+1), tag=t+2} straight from register
            const u64 pk = ((u64)(unsigned)(t + 2) << 32) |
                           (u64)__float_as_uint(unv);
            if (aN >= 0) gstore64(sb + aN, pk);
            if (aS >= 0) gstore64(sb + aS, pk);
            if (aW >= 0) gstore64(sb + aW, pk);
            if (aE >= 0) gstore64(sb + aE, pk);
        }
        __syncthreads();                       // B4: LDS state visible

        // ---- 3. receivers sample un ----
        if (recLds >= 0) out[recOut + t * NREC] = uN[recLds];

        pa ^= 1; pb ^= 1;
    }
}

// ---------------- host launch ----------------
extern "C" void kernel_launch(void* const* d_in, const int* in_sizes, int n_in,
                              void* d_out, int out_size, void* d_ws, size_t ws_size,
                              hipStream_t stream) {
    const float* vp = (const float*)d_in[0];
    const float* src = (const float*)d_in[1];
    const int* src_loc = (const int*)d_in[2];
    const int* rec_loc = (const int*)d_in[3];
    float* out = (float*)d_out;

    float* ws = (float*)d_ws;
    float* cst = ws;                           // 32 floats (keeps stage 128B-aligned)
    u64* stage = (u64*)(ws + 32);              // NBLKS*2*STAGE_CELLS packed cells

    // zero cst + stage (tags=0 everywhere; prologue publishes tag=1 cells)
    hipMemsetAsync(d_ws, 0,
                   (size_t)32 * sizeof(float) +
                   (size_t)NBLKS * 2 * STAGE_CELLS * sizeof(u64),
                   stream);
    vmax_kernel<<<1, 256, 0, stream>>>(vp, cst);
    persist_kernel<<<NBLKS, THREADS, 0, stream>>>(
        vp, src, src_loc, rec_loc, out, stage, cst);
}